// Round 17
// baseline (655.411 us; speedup 1.0000x reference)
//
#include <hip/hip_runtime.h>
#include <hip/hip_bf16.h>
#include <math.h>

#define NR 32768
#define DD 384
#define CDM 882
#define CDMP 896

typedef float f4 __attribute__((ext_vector_type(4)));
typedef float f32x4 __attribute__((ext_vector_type(4)));
typedef __bf16 bf16x8 __attribute__((ext_vector_type(8)));

__device__ inline f4 ld4(const float* p) { f4 v; __builtin_memcpy(&v, p, 16); return v; }
__device__ inline bf16x8 ld8h(const __bf16* p) { bf16x8 v; __builtin_memcpy(&v, p, 16); return v; }
__device__ inline void st8h(__bf16* p, bf16x8 v) { __builtin_memcpy(p, &v, 16); }

__device__ inline void gl_lds16(const void* g, void* l) {
  __builtin_amdgcn_global_load_lds(
      (const __attribute__((address_space(1))) void*)g,
      (__attribute__((address_space(3))) void*)l, 16, 0, 0);
}

__device__ inline float gred16(float v) {
#pragma unroll
  for (int o = 1; o < 16; o <<= 1) v += __shfl_xor(v, o, 64);
  return v;
}

// ---------------- weight transposes (18 square + corr in one launch) --------
struct WPtrs { const float* w[19]; };

__global__ __launch_bounds__(256) void trans_all_k(WPtrs P, __bf16* __restrict__ dst) {
  int wi = blockIdx.y;
  const float* W = P.w[wi];
  int i = blockIdx.x * 256 + threadIdx.x;
  if (wi < 18) {
    if (i >= DD * DD) return;
    int n = i / DD, k = i - n * DD;
    dst[(size_t)wi * DD * DD + i] = (__bf16)W[(size_t)k * DD + n];
  } else {
    if (i >= DD * CDMP) return;
    int n = i / CDMP, k = i - n * CDMP;
    dst[(size_t)18 * DD * DD + i] = (k < CDM) ? (__bf16)W[(size_t)k * DD + n] : (__bf16)0.f;
  }
}

// ---------------- GEMM params ----------------
struct GP {
  const void* A; const __bf16* WT; const float* bias; __bf16* OUT;
  const __bf16* XRES; const __bf16* GIN;
  const float* p0; const float* p1; const float* p2; const float* p3;
  float* fout; const float* net32; const float* inp32;
  const int* idx; const __bf16* zpage; int M; int K; int Kr;
};

__device__ __forceinline__ void mfma_block(const __bf16* As, const __bf16* Bs,
                                           f32x4 (&acc)[4][6], int wr, int wc,
                                           int fr, int fq) {
#pragma unroll
  for (int kk2 = 0; kk2 < 2; ++kk2) {
    bf16x8 af[4];
    bf16x8 bv[6];
#pragma unroll
    for (int mi = 0; mi < 4; ++mi) {
      int rr = wr + mi * 16 + fr;
      af[mi] = *reinterpret_cast<const bf16x8*>(
          &As[rr * 64 + (((fq + kk2 * 4) ^ (rr & 7)) << 3)]);
    }
#pragma unroll
    for (int ni = 0; ni < 6; ++ni) {
      int rr = wc + ni * 16 + fr;
      bv[ni] = *reinterpret_cast<const bf16x8*>(
          &Bs[rr * 64 + (((fq + kk2 * 4) ^ (rr & 7)) << 3)]);
    }
#pragma unroll
    for (int mi = 0; mi < 4; ++mi)
#pragma unroll
      for (int ni = 0; ni < 6; ++ni)
        acc[mi][ni] = __builtin_amdgcn_mfma_f32_16x16x32_bf16(af[mi], bv[ni],
                                                              acc[mi][ni], 0, 0, 0);
  }
}

__device__ __forceinline__ void zero_acc(f32x4 (&acc)[4][6]) {
#pragma unroll
  for (int a = 0; a < 4; ++a)
#pragma unroll
    for (int b = 0; b < 6; ++b)
#pragma unroll
      for (int j = 0; j < 4; ++j) acc[a][b][j] = 0.f;
}

// ---------- epilogue (BM=128, BN=384, 8 waves, acc 4x6) ----------
// EPI: 0 store, 1 relu, 2 OUT+=v, 4 relu(LN(v)), 5 LN(net+inp+v),
//      6 x=LN(XRES+sig(GIN)*v), 7 final: net9=XRES+sig(GIN)*v -> fp32 out + heads
template <int EPI>
__device__ __forceinline__ void epilogue(const GP& gp, f32x4 (&acc)[4][6],
                                         __bf16* sm, int m0, int w, int lane) {
  const int fr = lane & 15, fq = lane >> 4;
  const int wr = (w >> 2) * 64, wc = (w & 3) * 96;
  const int nw = w & 3;
  float bcol[6];
#pragma unroll
  for (int ni = 0; ni < 6; ++ni) bcol[ni] = gp.bias[wc + ni * 16 + fr];
#pragma unroll
  for (int mi = 0; mi < 4; ++mi)
#pragma unroll
    for (int ni = 0; ni < 6; ++ni)
#pragma unroll
      for (int j = 0; j < 4; ++j) acc[mi][ni][j] += bcol[ni];

  if constexpr (EPI <= 2) {
#pragma unroll
    for (int mi = 0; mi < 4; ++mi)
#pragma unroll
      for (int ni = 0; ni < 6; ++ni) {
        int col = wc + ni * 16 + fr;
#pragma unroll
        for (int j = 0; j < 4; ++j) {
          int row = m0 + wr + mi * 16 + fq * 4 + j;
          size_t o = (size_t)row * DD + col;
          float v = acc[mi][ni][j];
          if constexpr (EPI == 0) gp.OUT[o] = (__bf16)v;
          else if constexpr (EPI == 1) gp.OUT[o] = (__bf16)fmaxf(v, 0.f);
          else gp.OUT[o] = (__bf16)((float)gp.OUT[o] + v);
        }
      }
  } else {
    if constexpr (EPI == 5) {
#pragma unroll
      for (int mi = 0; mi < 4; ++mi)
#pragma unroll
        for (int ni = 0; ni < 6; ++ni) {
          int col = wc + ni * 16 + fr;
#pragma unroll
          for (int j = 0; j < 4; ++j) {
            int row = m0 + wr + mi * 16 + fq * 4 + j;
            size_t o = (size_t)row * DD + col;
            acc[mi][ni][j] += gp.net32[o] + gp.inp32[o];
          }
        }
    }
    if constexpr (EPI == 6 || EPI == 7) {
#pragma unroll
      for (int mi = 0; mi < 4; ++mi)
#pragma unroll
        for (int ni = 0; ni < 6; ++ni) {
          int col = wc + ni * 16 + fr;
#pragma unroll
          for (int j = 0; j < 4; ++j) {
            int row = m0 + wr + mi * 16 + fq * 4 + j;
            size_t o = (size_t)row * DD + col;
            float gl = (float)gp.GIN[o];
            float sg = 1.f / (1.f + expf(-gl));
            acc[mi][ni][j] = (float)gp.XRES[o] + sg * acc[mi][ni][j];
          }
        }
    }
    __syncthreads();
    if constexpr (EPI != 7) {
      float s1[4][4], s2[4][4];
#pragma unroll
      for (int mi = 0; mi < 4; ++mi)
#pragma unroll
        for (int j = 0; j < 4; ++j) { s1[mi][j] = 0.f; s2[mi][j] = 0.f; }
#pragma unroll
      for (int mi = 0; mi < 4; ++mi)
#pragma unroll
        for (int ni = 0; ni < 6; ++ni)
#pragma unroll
          for (int j = 0; j < 4; ++j) {
            float v = acc[mi][ni][j];
            s1[mi][j] += v;
            s2[mi][j] += v * v;
          }
#pragma unroll
      for (int o = 1; o < 16; o <<= 1)
#pragma unroll
        for (int mi = 0; mi < 4; ++mi)
#pragma unroll
          for (int j = 0; j < 4; ++j) {
            s1[mi][j] += __shfl_xor(s1[mi][j], o, 64);
            s2[mi][j] += __shfl_xor(s2[mi][j], o, 64);
          }
      float* lsum = (float*)sm;
      float* lsq = lsum + 512;
      if (fr == 0) {
#pragma unroll
        for (int mi = 0; mi < 4; ++mi)
#pragma unroll
          for (int j = 0; j < 4; ++j) {
            int rr = wr + mi * 16 + fq * 4 + j;
            lsum[rr * 4 + nw] = s1[mi][j];
            lsq[rr * 4 + nw] = s2[mi][j];
          }
      }
      __syncthreads();
      float mn[4][4], rs[4][4];
#pragma unroll
      for (int mi = 0; mi < 4; ++mi)
#pragma unroll
        for (int j = 0; j < 4; ++j) {
          int rr = wr + mi * 16 + fq * 4 + j;
          float S1 = lsum[rr * 4] + lsum[rr * 4 + 1] + lsum[rr * 4 + 2] + lsum[rr * 4 + 3];
          float S2 = lsq[rr * 4] + lsq[rr * 4 + 1] + lsq[rr * 4 + 2] + lsq[rr * 4 + 3];
          float m = S1 * (1.f / 384.f);
          float va = S2 * (1.f / 384.f) - m * m;
          mn[mi][j] = m;
          rs[mi][j] = rsqrtf(va + 1e-3f);
        }
#pragma unroll
      for (int ni = 0; ni < 6; ++ni) {
        int col = wc + ni * 16 + fr;
        float gg = gp.p0[col], bb = gp.p1[col];
#pragma unroll
        for (int mi = 0; mi < 4; ++mi)
#pragma unroll
          for (int j = 0; j < 4; ++j) {
            int row = m0 + wr + mi * 16 + fq * 4 + j;
            float y = (acc[mi][ni][j] - mn[mi][j]) * rs[mi][j] * gg + bb;
            if constexpr (EPI == 4) y = fmaxf(y, 0.f);
            gp.OUT[(size_t)row * DD + col] = (__bf16)y;
          }
      }
    } else {
      float c0[6], c1[6], c2[6], c3[6];
#pragma unroll
      for (int ni = 0; ni < 6; ++ni) {
        int col = wc + ni * 16 + fr;
        c0[ni] = gp.p0[2 * col];
        c1[ni] = gp.p0[2 * col + 1];
        c2[ni] = gp.p2[2 * col];
        c3[ni] = gp.p2[2 * col + 1];
      }
      float dt[4][4][4];
#pragma unroll
      for (int mi = 0; mi < 4; ++mi)
#pragma unroll
        for (int j = 0; j < 4; ++j)
#pragma unroll
          for (int q = 0; q < 4; ++q) dt[mi][j][q] = 0.f;
#pragma unroll
      for (int mi = 0; mi < 4; ++mi)
#pragma unroll
        for (int ni = 0; ni < 6; ++ni) {
          int col = wc + ni * 16 + fr;
#pragma unroll
          for (int j = 0; j < 4; ++j) {
            int row = m0 + wr + mi * 16 + fq * 4 + j;
            float v = acc[mi][ni][j];
            gp.fout[(size_t)row * DD + col] = v;
            float r = fmaxf(v, 0.f);
            dt[mi][j][0] += r * c0[ni];
            dt[mi][j][1] += r * c1[ni];
            dt[mi][j][2] += r * c2[ni];
            dt[mi][j][3] += r * c3[ni];
          }
        }
#pragma unroll
      for (int o = 1; o < 16; o <<= 1)
#pragma unroll
        for (int mi = 0; mi < 4; ++mi)
#pragma unroll
          for (int j = 0; j < 4; ++j)
#pragma unroll
            for (int q = 0; q < 4; ++q)
              dt[mi][j][q] += __shfl_xor(dt[mi][j][q], o, 64);
      float* lt = (float*)sm;
      if (fr == 0) {
#pragma unroll
        for (int mi = 0; mi < 4; ++mi)
#pragma unroll
          for (int j = 0; j < 4; ++j) {
            int rr = wr + mi * 16 + fq * 4 + j;
#pragma unroll
            for (int q = 0; q < 4; ++q) lt[(rr * 4 + nw) * 4 + q] = dt[mi][j][q];
          }
      }
      __syncthreads();
      if (nw == 0 && fr == 0) {
        float* fd = gp.fout + (size_t)NR * DD;
        float* fw = fd + (size_t)NR * 2;
#pragma unroll
        for (int mi = 0; mi < 4; ++mi)
#pragma unroll
          for (int j = 0; j < 4; ++j) {
            int rr = wr + mi * 16 + fq * 4 + j;
            int row = m0 + rr;
            float T[4];
#pragma unroll
            for (int q = 0; q < 4; ++q)
              T[q] = lt[(rr * 4 + 0) * 4 + q] + lt[(rr * 4 + 1) * 4 + q] +
                     lt[(rr * 4 + 2) * 4 + q] + lt[(rr * 4 + 3) * 4 + q];
            fd[2 * row] = T[0] + gp.p1[0];
            fd[2 * row + 1] = T[1] + gp.p1[1];
            fw[2 * row] = 1.f / (1.f + expf(-(T[2] + gp.p3[0])));
            fw[2 * row + 1] = 1.f / (1.f + expf(-(T[3] + gp.p3[1])));
          }
      }
    }
  }
}

// ---- MFMA GEMM, BM=128 BN=384, BK=128: 16 loads/thread in flight per stage --
// LDS 128 KB: As0 16K | As1 16K | Bs0 48K | Bs1 48K (two 64-wide halves).
template <int EPI, int AFP32>
__global__ __launch_bounds__(512, 1) void gemm_k(GP gp) {
  __shared__ __align__(16) __bf16 sm[65536];
  const int t = threadIdx.x;
  const int w = t >> 6, lane = t & 63;
  const int m0 = blockIdx.x * 128;
  const int fr = lane & 15, fq = lane >> 4;
  const int wr = (w >> 2) * 64, wc = (w & 3) * 96;
  const int K = gp.K;

  const __bf16* aptr[2];
  int aadv[2];
  const __bf16* bptr[6];
#pragma unroll
  for (int j = 0; j < 2; ++j) {
    int rloc = w * 16 + j * 8 + (lane >> 3);
    int cch = (lane & 7) ^ (rloc & 7);
    if constexpr (!AFP32) {
      int ar = gp.idx ? gp.idx[m0 + rloc] : (m0 + rloc);
      if (ar >= 0) { aptr[j] = (const __bf16*)gp.A + (size_t)ar * K + cch * 8; aadv[j] = 64; }
      else { aptr[j] = gp.zpage; aadv[j] = 0; }
    }
  }
#pragma unroll
  for (int j = 0; j < 6; ++j) {
    int rloc = w * 48 + j * 8 + (lane >> 3);
    int cch = (lane & 7) ^ (rloc & 7);
    bptr[j] = gp.WT + (size_t)rloc * K + cch * 8;
  }
  const float* Af = (const float*)gp.A;
  const int Kr = gp.Kr;
  const int NT = K >> 7;  // K-steps of 128

  f32x4 acc[4][6];
  zero_acc(acc);

  for (int tt = 0; tt < NT; ++tt) {
    if (tt) __syncthreads();
    // stage both 64-wide halves back-to-back: 16 loads in flight
#pragma unroll
    for (int h = 0; h < 2; ++h) {
      __bf16* As = sm + h * 8192;
      __bf16* Bs = sm + 16384 + h * 24576;
      if constexpr (AFP32) {
#pragma unroll
        for (int j = 0; j < 2; ++j) {
          int rr = (t >> 3) + 64 * j;
          int cc = t & 7;
          int kb = (tt << 7) + (h << 6) + cc * 8;
          const float* ap = Af + (size_t)(m0 + rr) * Kr + kb;
          bf16x8 hv;
          if (kb + 8 <= Kr) {
            f4 v0 = ld4(ap), v1 = ld4(ap + 4);
#pragma unroll
            for (int e = 0; e < 4; ++e) { hv[e] = (__bf16)v0[e]; hv[4 + e] = (__bf16)v1[e]; }
          } else {
#pragma unroll
            for (int e = 0; e < 8; ++e) hv[e] = (kb + e < Kr) ? (__bf16)ap[e] : (__bf16)0.f;
          }
          *reinterpret_cast<bf16x8*>(&As[rr * 64 + ((cc ^ (rr & 7)) << 3)]) = hv;
        }
      } else {
#pragma unroll
        for (int j = 0; j < 2; ++j) {
          gl_lds16(aptr[j], &As[(w * 16 + j * 8) * 64]);
          aptr[j] += aadv[j];
        }
      }
#pragma unroll
      for (int j = 0; j < 6; ++j) {
        gl_lds16(bptr[j], &Bs[(w * 48 + j * 8) * 64]);
        bptr[j] += 64;
      }
    }
    __syncthreads();
#pragma unroll
    for (int h = 0; h < 2; ++h)
      mfma_block(sm + h * 8192, sm + 16384 + h * 24576, acc, wr, wc, fr, fq);
  }
  __syncthreads();  // all waves done with LDS before epilogue reuses it
  epilogue<EPI>(gp, acc, sm, m0, w, lane);
}

// ---------------- fused addgather + LayerNorm ----------------
__global__ __launch_bounds__(256) void ln_ag_k(const __bf16* __restrict__ X,
                                               const __bf16* __restrict__ z,
                                               const int* __restrict__ gid,
                                               const float* __restrict__ g,
                                               const float* __restrict__ b,
                                               __bf16* __restrict__ out) {
  int w = threadIdx.x >> 6, lane = threadIdx.x & 63;
  int s = lane & 15, qq = lane >> 4;
  int row = blockIdx.x * 16 + w * 4 + qq;
  int gr = gid[row];
  size_t base = (size_t)row * DD;
  size_t zbase = (size_t)gr * DD;
  float v[24];
#pragma unroll
  for (int i = 0; i < 3; ++i) {
    int col = (s + 16 * i) * 8;
    bf16x8 h = ld8h(X + base + col);
    bf16x8 zz = ld8h(z + zbase + col);
#pragma unroll
    for (int e = 0; e < 8; ++e) v[i * 8 + e] = (float)h[e] + (float)zz[e];
  }
  float sm = 0.f;
#pragma unroll
  for (int i = 0; i < 24; ++i) sm += v[i];
  sm = gred16(sm);
  float mean = sm * (1.f / 384.f);
  float qs = 0.f;
#pragma unroll
  for (int i = 0; i < 24; ++i) { float d = v[i] - mean; qs += d * d; }
  qs = gred16(qs);
  float rs = rsqrtf(qs * (1.f / 384.f) + 1e-3f);
#pragma unroll
  for (int i = 0; i < 3; ++i) {
    int col = (s + 16 * i) * 8;
    f4 g0 = ld4(g + col), g1 = ld4(g + col + 4);
    f4 b0 = ld4(b + col), b1 = ld4(b + col + 4);
    bf16x8 o;
#pragma unroll
    for (int e = 0; e < 4; ++e) {
      o[e] = (__bf16)((v[i * 8 + e] - mean) * rs * g0[e] + b0[e]);
      o[4 + e] = (__bf16)((v[i * 8 + 4 + e] - mean) * rs * g1[e] + b1[e]);
    }
    st8h(out + base + col, o);
  }
}

// ---------------- segment rowlist build ----------------
__global__ __launch_bounds__(256) void hist2_k(const int* __restrict__ ukk,
                                               const int* __restrict__ ujk,
                                               int* __restrict__ ckk,
                                               int* __restrict__ cij) {
  int i = blockIdx.x * 256 + threadIdx.x;
  atomicAdd(&ckk[ukk[i]], 1);
  atomicAdd(&cij[ujk[i]], 1);
}

__device__ inline void scan_body(const int* cnt, int* off, int* curb, int G, int* ls) {
  int t = threadIdx.x;
  int per = G / 256;
  int base = t * per;
  int s = 0;
  for (int i = 0; i < per; ++i) s += cnt[base + i];
  ls[t] = s;
  __syncthreads();
  for (int o = 1; o < 256; o <<= 1) {
    int v = (t >= o) ? ls[t - o] : 0;
    __syncthreads();
    ls[t] += v;
    __syncthreads();
  }
  int run = (t == 0) ? 0 : ls[t - 1];
  for (int i = 0; i < per; ++i) {
    off[base + i] = run;
    run += cnt[base + i];
    curb[base + i] = 0;
  }
  if (t == 255) off[G] = run;
}

__global__ __launch_bounds__(256) void scan2_k(const int* ckk, int* okk, int* qkk,
                                               const int* cij, int* oij, int* qij) {
  __shared__ int ls[256];
  if (blockIdx.x == 0) scan_body(ckk, okk, qkk, 4096, ls);
  else scan_body(cij, oij, qij, 512, ls);
}

__global__ __launch_bounds__(256) void scatter2_k(const int* __restrict__ ukk,
                                                  const int* __restrict__ ujk,
                                                  const int* __restrict__ okk,
                                                  int* __restrict__ qkk,
                                                  int* __restrict__ rkk,
                                                  const int* __restrict__ oij,
                                                  int* __restrict__ qij,
                                                  int* __restrict__ rij) {
  int i = blockIdx.x * 256 + threadIdx.x;
  int g1 = ukk[i];
  rkk[okk[g1] + atomicAdd(&qkk[g1], 1)] = i;
  int g2 = ujk[i];
  rij[oij[g2] + atomicAdd(&qij[g2], 1)] = i;
}

// one block per group, 384 threads = one per column
__global__ __launch_bounds__(384) void segagg_k(const __bf16* __restrict__ L,
                                                const __bf16* __restrict__ Ft,
                                                const int* __restrict__ rows,
                                                const int* __restrict__ off,
                                                float* __restrict__ yb) {
  int g = blockIdx.x;
  int c = threadIdx.x;
  int s = off[g], e = off[g + 1];
  float mx = -3.0e38f;
  for (int p = s; p < e; ++p) {
    int r = rows[p];
    mx = fmaxf(mx, (float)L[(size_t)r * DD + c]);
  }
  float num = 0.f, den = 0.f;
  for (int p = s; p < e; ++p) {
    int r = rows[p];
    float lv = (float)L[(size_t)r * DD + c];
    float fv = (float)Ft[(size_t)r * DD + c];
    float ev = expf(lv - mx);
    den += ev;
    num += fv * ev;
  }
  yb[(size_t)g * DD + c] = num / (den + 1e-12f);
}

__global__ __launch_bounds__(256) void addgather_k(__bf16* __restrict__ X,
                                                   const __bf16* __restrict__ z,
                                                   const int* __restrict__ gid) {
  int i = blockIdx.x * 256 + threadIdx.x;
  int row = i / 48, c = (i - row * 48) * 8;
  int g = gid[row];
  size_t lo = (size_t)row * DD + c;
  bf16x8 a = ld8h(X + lo);
  bf16x8 zz = ld8h(z + (size_t)g * DD + c);
  bf16x8 o;
#pragma unroll
  for (int e = 0; e < 8; ++e) o[e] = (__bf16)((float)a[e] + (float)zz[e]);
  st8h(X + lo, o);
}

extern "C" void kernel_launch(void* const* d_in, const int* in_sizes, int n_in,
                              void* d_out, int out_size, void* d_ws, size_t ws_size,
                              hipStream_t stream) {
  const float* in_net = (const float*)d_in[0];
  const float* in_inp = (const float*)d_in[1];
  const float* in_corr = (const float*)d_in[2];
  const int* nix = (const int*)d_in[3];
  const int* njx = (const int*)d_in[4];
  const int* ukk = (const int*)d_in[5];
  const int* ujk = (const int*)d_in[6];
  auto F = [&](int i) { return (const float*)d_in[i]; };

  constexpr size_t MiB = 1024 * 1024;
  constexpr size_t SZ_ACT = (size_t)NR * DD * 2;
  char* ws = (char*)d_ws;
  __bf16* T2b = (__bf16*)(ws);
  __bf16* Fb = (__bf16*)(ws + SZ_ACT);
  __bf16* zb = (__bf16*)(ws + 2 * SZ_ACT);         // 3 MiB
  float* yb = (float*)(ws + 2 * SZ_ACT + 3 * MiB); // 6 MiB
  __bf16* T1b = (__bf16*)(ws + 60 * MiB);          // 24 MiB
  char* p = ws + 84 * MiB;
  int* rows_kk = (int*)p; p += (size_t)NR * 4;
  int* rows_ij = (int*)p; p += (size_t)NR * 4;
  int* off_kk = (int*)p; p += 8192 * 4;
  int* off_ij = (int*)p; p += 1024 * 4;
  int* cnt_kk = (int*)p; p += 4096 * 4;
  int* cnt_ij = (int*)p; p += 512 * 4;
  int* curb_kk = (int*)p; p += 4096 * 4;
  int* curb_ij = (int*)p; p += 512 * 4;
  __bf16* wt_all = (__bf16*)p; p += (size_t)18 * DD * DD * 2;
  __bf16* wt_corr1 = (__bf16*)p; p += (size_t)DD * CDMP * 2;
  __bf16* zpage = (__bf16*)p;

  const int widx[18] = {17, 19, 21, 23, 25, 27, 29, 31, 33, 35, 39, 41, 43, 47, 49, 51, 9, 13};
  WPtrs P;
  for (int i = 0; i < 18; ++i) P.w[i] = F(widx[i]);
  P.w[18] = F(7);
  auto WTp = [&](int i) { return wt_all + (size_t)i * DD * DD; };

  hipMemsetAsync(zpage, 0, 256, stream);
  hipMemsetAsync(cnt_kk, 0, 4096 * 4, stream);
  hipMemsetAsync(cnt_ij, 0, 512 * 4, stream);
  trans_all_k<<<dim3(1344, 19), 256, 0, stream>>>(P, wt_all);
  hist2_k<<<NR / 256, 256, 0, stream>>>(ukk, ujk, cnt_kk, cnt_ij);
  scan2_k<<<2, 256, 0, stream>>>(cnt_kk, off_kk, curb_kk, cnt_ij, off_ij, curb_ij);
  scatter2_k<<<NR / 256, 256, 0, stream>>>(ukk, ujk, off_kk, curb_kk, rows_kk,
                                           off_ij, curb_ij, rows_ij);

  auto G = [&](int epi, const void* A, const __bf16* WT, const float* bias,
               __bf16* OUT, const __bf16* XRES, const __bf16* GIN,
               const float* p0, const float* p1, const float* p2, const float* p3,
               float* fout, const float* n32, const float* i32,
               const int* idx, int M, int K, int Kr) {
    GP gp{A, WT, bias, OUT, XRES, GIN, p0, p1, p2, p3, fout, n32, i32, idx, zpage, M, K, Kr};
    dim3 g(M / 128), b(512);
    switch (epi) {
      case 0: gemm_k<0, 0><<<g, b, 0, stream>>>(gp); break;
      case 1: gemm_k<1, 0><<<g, b, 0, stream>>>(gp); break;
      case 2: gemm_k<2, 0><<<g, b, 0, stream>>>(gp); break;
      case 4: gemm_k<4, 0><<<g, b, 0, stream>>>(gp); break;
      case 5: gemm_k<5, 0><<<g, b, 0, stream>>>(gp); break;
      case 6: gemm_k<6, 0><<<g, b, 0, stream>>>(gp); break;
      case 7: gemm_k<7, 0><<<g, b, 0, stream>>>(gp); break;
      case 8: gemm_k<0, 1><<<g, b, 0, stream>>>(gp); break;  // AFP32 store
      case 9: gemm_k<1, 1><<<g, b, 0, stream>>>(gp); break;  // AFP32 relu
    }
  };
  auto GS = [&](int epi, const void* A, const __bf16* WT, const float* bias,
                __bf16* OUT, const int* idx, int M, int K) {
    G(epi, A, WT, bias, OUT, nullptr, nullptr, nullptr, nullptr, nullptr, nullptr,
      nullptr, nullptr, nullptr, idx, M, K, K);
  };

  const int SEGB = NR * 48 / 256;

  // corr encoder (fp32 A read in-GEMM; Kr = 882 real row stride)
  G(9, in_corr, wt_corr1, F(8), T1b, nullptr, nullptr, nullptr, nullptr, nullptr,
    nullptr, nullptr, nullptr, nullptr, nullptr, NR, CDMP, CDM);       // relu(h1)
  G(4, T1b, WTp(16), F(10), T2b, nullptr, nullptr, F(11), F(12), nullptr, nullptr,
    nullptr, nullptr, nullptr, nullptr, NR, DD, DD);                   // relu(LN(h2))
  G(5, T2b, WTp(17), F(14), T1b, nullptr, nullptr, F(15), F(16), nullptr, nullptr,
    nullptr, in_net, in_inp, nullptr, NR, DD, DD);                     // T1b = net2
  // c1
  GS(1, T1b, WTp(0), F(18), T2b, nix, NR, DD);
  GS(2, T2b, WTp(1), F(20), T1b, nullptr, NR, DD);                     // net3
  // c2
  GS(1, T1b, WTp(2), F(22), T2b, njx, NR, DD);
  GS(2, T2b, WTp(3), F(24), T1b, nullptr, NR, DD);                     // net4
  // kk soft-agg
  GS(0, T1b, WTp(5), F(28), T2b, nullptr, NR, DD);                     // logits
  GS(0, T1b, WTp(4), F(26), Fb, nullptr, NR, DD);                      // feats
  segagg_k<<<4096, 384, 0, stream>>>(T2b, Fb, rows_kk, off_kk, yb);
  GS(8, yb, WTp(6), F(30), zb, nullptr, 4096, DD);
  addgather_k<<<SEGB, 256, 0, stream>>>(T1b, zb, ukk);                 // net5
  // ij soft-agg
  GS(0, T1b, WTp(8), F(34), T2b, nullptr, NR, DD);
  GS(0, T1b, WTp(7), F(32), Fb, nullptr, NR, DD);
  segagg_k<<<512, 384, 0, stream>>>(T2b, Fb, rows_ij, off_ij, yb);
  GS(8, yb, WTp(9), F(36), zb, nullptr, 512, DD);
  ln_ag_k<<<NR / 16, 256, 0, stream>>>(T1b, zb, ujk, F(37), F(38), T2b);  // x1
  // gated residual 1
  GS(0, T2b, WTp(10), F(40), Fb, nullptr, NR, DD);                     // gate logits
  GS(1, T2b, WTp(11), F(42), T1b, nullptr, NR, DD);                    // r1
  G(6, T1b, WTp(12), F(44), T2b, T2b, Fb, F(45), F(46), nullptr, nullptr,
    nullptr, nullptr, nullptr, nullptr, NR, DD, DD);                   // x2 = LN2(net7)
  // gated residual 2 + final heads
  GS(0, T2b, WTp(13), F(48), Fb, nullptr, NR, DD);
  GS(1, T2b, WTp(14), F(50), T1b, nullptr, NR, DD);
  G(7, T1b, WTp(15), F(52), nullptr, T2b, Fb, F(53), F(54), F(55), F(56),
    (float*)d_out, nullptr, nullptr, nullptr, NR, DD, DD);             // out
}

// Round 18
// 622.033 us; speedup vs baseline: 1.0537x; 1.0537x over previous
//
#include <hip/hip_runtime.h>
#include <hip/hip_bf16.h>
#include <math.h>

#define NR 32768
#define DD 384
#define CDM 882
#define CDMP 896

typedef float f4 __attribute__((ext_vector_type(4)));
typedef float f32x4 __attribute__((ext_vector_type(4)));
typedef __bf16 bf16x8 __attribute__((ext_vector_type(8)));

__device__ inline f4 ld4(const float* p) { f4 v; __builtin_memcpy(&v, p, 16); return v; }
__device__ inline bf16x8 ld8h(const __bf16* p) { bf16x8 v; __builtin_memcpy(&v, p, 16); return v; }
__device__ inline void st8h(__bf16* p, bf16x8 v) { __builtin_memcpy(p, &v, 16); }

__device__ inline void gl_lds16(const void* g, void* l) {
  __builtin_amdgcn_global_load_lds(
      (const __attribute__((address_space(1))) void*)g,
      (__attribute__((address_space(3))) void*)l, 16, 0, 0);
}

__device__ inline float gred16(float v) {
#pragma unroll
  for (int o = 1; o < 16; o <<= 1) v += __shfl_xor(v, o, 64);
  return v;
}

// ---------------- weight transposes (18 square + corr in one launch) --------
struct WPtrs { const float* w[19]; };

__global__ __launch_bounds__(256) void trans_all_k(WPtrs P, __bf16* __restrict__ dst) {
  int wi = blockIdx.y;
  const float* W = P.w[wi];
  int i = blockIdx.x * 256 + threadIdx.x;
  if (wi < 18) {
    if (i >= DD * DD) return;
    int n = i / DD, k = i - n * DD;
    dst[(size_t)wi * DD * DD + i] = (__bf16)W[(size_t)k * DD + n];
  } else {
    if (i >= DD * CDMP) return;
    int n = i / CDMP, k = i - n * CDMP;
    dst[(size_t)18 * DD * DD + i] = (k < CDM) ? (__bf16)W[(size_t)k * DD + n] : (__bf16)0.f;
  }
}

// ---------------- GEMM params ----------------
struct GP {
  const void* A; const __bf16* WT; const float* bias; __bf16* OUT;
  const __bf16* XRES; const __bf16* GIN;
  const float* p0; const float* p1; const float* p2; const float* p3;
  float* fout; const float* net32; const float* inp32;
  const int* idx; const __bf16* zpage; int M; int K; int Kr;
};

__device__ __forceinline__ void mfma_block(const __bf16* As, const __bf16* Bs,
                                           f32x4 (&acc)[4][6], int wr, int wc,
                                           int fr, int fq) {
#pragma unroll
  for (int kk2 = 0; kk2 < 2; ++kk2) {
    bf16x8 af[4];
    bf16x8 bv[6];
#pragma unroll
    for (int mi = 0; mi < 4; ++mi) {
      int rr = wr + mi * 16 + fr;
      af[mi] = *reinterpret_cast<const bf16x8*>(
          &As[rr * 64 + (((fq + kk2 * 4) ^ (rr & 7)) << 3)]);
    }
#pragma unroll
    for (int ni = 0; ni < 6; ++ni) {
      int rr = wc + ni * 16 + fr;
      bv[ni] = *reinterpret_cast<const bf16x8*>(
          &Bs[rr * 64 + (((fq + kk2 * 4) ^ (rr & 7)) << 3)]);
    }
#pragma unroll
    for (int mi = 0; mi < 4; ++mi)
#pragma unroll
      for (int ni = 0; ni < 6; ++ni)
        acc[mi][ni] = __builtin_amdgcn_mfma_f32_16x16x32_bf16(af[mi], bv[ni],
                                                              acc[mi][ni], 0, 0, 0);
  }
}

__device__ __forceinline__ void zero_acc(f32x4 (&acc)[4][6]) {
#pragma unroll
  for (int a = 0; a < 4; ++a)
#pragma unroll
    for (int b = 0; b < 6; ++b)
#pragma unroll
      for (int j = 0; j < 4; ++j) acc[a][b][j] = 0.f;
}

// ---------- epilogue (BM=128, BN=384, 8 waves, acc 4x6) ----------
template <int EPI>
__device__ __forceinline__ void epilogue(const GP& gp, f32x4 (&acc)[4][6],
                                         __bf16* sm, int m0, int w, int lane) {
  const int fr = lane & 15, fq = lane >> 4;
  const int wr = (w >> 2) * 64, wc = (w & 3) * 96;
  const int nw = w & 3;
  float bcol[6];
#pragma unroll
  for (int ni = 0; ni < 6; ++ni) bcol[ni] = gp.bias[wc + ni * 16 + fr];
#pragma unroll
  for (int mi = 0; mi < 4; ++mi)
#pragma unroll
    for (int ni = 0; ni < 6; ++ni)
#pragma unroll
      for (int j = 0; j < 4; ++j) acc[mi][ni][j] += bcol[ni];

  if constexpr (EPI <= 2) {
#pragma unroll
    for (int mi = 0; mi < 4; ++mi)
#pragma unroll
      for (int ni = 0; ni < 6; ++ni) {
        int col = wc + ni * 16 + fr;
#pragma unroll
        for (int j = 0; j < 4; ++j) {
          int row = m0 + wr + mi * 16 + fq * 4 + j;
          size_t o = (size_t)row * DD + col;
          float v = acc[mi][ni][j];
          if constexpr (EPI == 0) gp.OUT[o] = (__bf16)v;
          else if constexpr (EPI == 1) gp.OUT[o] = (__bf16)fmaxf(v, 0.f);
          else gp.OUT[o] = (__bf16)((float)gp.OUT[o] + v);
        }
      }
  } else {
    if constexpr (EPI == 5) {
#pragma unroll
      for (int mi = 0; mi < 4; ++mi)
#pragma unroll
        for (int ni = 0; ni < 6; ++ni) {
          int col = wc + ni * 16 + fr;
#pragma unroll
          for (int j = 0; j < 4; ++j) {
            int row = m0 + wr + mi * 16 + fq * 4 + j;
            size_t o = (size_t)row * DD + col;
            acc[mi][ni][j] += gp.net32[o] + gp.inp32[o];
          }
        }
    }
    if constexpr (EPI == 6 || EPI == 7) {
#pragma unroll
      for (int mi = 0; mi < 4; ++mi)
#pragma unroll
        for (int ni = 0; ni < 6; ++ni) {
          int col = wc + ni * 16 + fr;
#pragma unroll
          for (int j = 0; j < 4; ++j) {
            int row = m0 + wr + mi * 16 + fq * 4 + j;
            size_t o = (size_t)row * DD + col;
            float gl = (float)gp.GIN[o];
            float sg = 1.f / (1.f + expf(-gl));
            acc[mi][ni][j] = (float)gp.XRES[o] + sg * acc[mi][ni][j];
          }
        }
    }
    __syncthreads();
    if constexpr (EPI != 7) {
      float s1[4][4], s2[4][4];
#pragma unroll
      for (int mi = 0; mi < 4; ++mi)
#pragma unroll
        for (int j = 0; j < 4; ++j) { s1[mi][j] = 0.f; s2[mi][j] = 0.f; }
#pragma unroll
      for (int mi = 0; mi < 4; ++mi)
#pragma unroll
        for (int ni = 0; ni < 6; ++ni)
#pragma unroll
          for (int j = 0; j < 4; ++j) {
            float v = acc[mi][ni][j];
            s1[mi][j] += v;
            s2[mi][j] += v * v;
          }
#pragma unroll
      for (int o = 1; o < 16; o <<= 1)
#pragma unroll
        for (int mi = 0; mi < 4; ++mi)
#pragma unroll
          for (int j = 0; j < 4; ++j) {
            s1[mi][j] += __shfl_xor(s1[mi][j], o, 64);
            s2[mi][j] += __shfl_xor(s2[mi][j], o, 64);
          }
      float* lsum = (float*)sm;
      float* lsq = lsum + 512;
      if (fr == 0) {
#pragma unroll
        for (int mi = 0; mi < 4; ++mi)
#pragma unroll
          for (int j = 0; j < 4; ++j) {
            int rr = wr + mi * 16 + fq * 4 + j;
            lsum[rr * 4 + nw] = s1[mi][j];
            lsq[rr * 4 + nw] = s2[mi][j];
          }
      }
      __syncthreads();
      float mn[4][4], rs[4][4];
#pragma unroll
      for (int mi = 0; mi < 4; ++mi)
#pragma unroll
        for (int j = 0; j < 4; ++j) {
          int rr = wr + mi * 16 + fq * 4 + j;
          float S1 = lsum[rr * 4] + lsum[rr * 4 + 1] + lsum[rr * 4 + 2] + lsum[rr * 4 + 3];
          float S2 = lsq[rr * 4] + lsq[rr * 4 + 1] + lsq[rr * 4 + 2] + lsq[rr * 4 + 3];
          float m = S1 * (1.f / 384.f);
          float va = S2 * (1.f / 384.f) - m * m;
          mn[mi][j] = m;
          rs[mi][j] = rsqrtf(va + 1e-3f);
        }
#pragma unroll
      for (int ni = 0; ni < 6; ++ni) {
        int col = wc + ni * 16 + fr;
        float gg = gp.p0[col], bb = gp.p1[col];
#pragma unroll
        for (int mi = 0; mi < 4; ++mi)
#pragma unroll
          for (int j = 0; j < 4; ++j) {
            int row = m0 + wr + mi * 16 + fq * 4 + j;
            float y = (acc[mi][ni][j] - mn[mi][j]) * rs[mi][j] * gg + bb;
            if constexpr (EPI == 4) y = fmaxf(y, 0.f);
            gp.OUT[(size_t)row * DD + col] = (__bf16)y;
          }
      }
    } else {
      float c0[6], c1[6], c2[6], c3[6];
#pragma unroll
      for (int ni = 0; ni < 6; ++ni) {
        int col = wc + ni * 16 + fr;
        c0[ni] = gp.p0[2 * col];
        c1[ni] = gp.p0[2 * col + 1];
        c2[ni] = gp.p2[2 * col];
        c3[ni] = gp.p2[2 * col + 1];
      }
      float dt[4][4][4];
#pragma unroll
      for (int mi = 0; mi < 4; ++mi)
#pragma unroll
        for (int j = 0; j < 4; ++j)
#pragma unroll
          for (int q = 0; q < 4; ++q) dt[mi][j][q] = 0.f;
#pragma unroll
      for (int mi = 0; mi < 4; ++mi)
#pragma unroll
        for (int ni = 0; ni < 6; ++ni) {
          int col = wc + ni * 16 + fr;
#pragma unroll
          for (int j = 0; j < 4; ++j) {
            int row = m0 + wr + mi * 16 + fq * 4 + j;
            float v = acc[mi][ni][j];
            gp.fout[(size_t)row * DD + col] = v;
            float r = fmaxf(v, 0.f);
            dt[mi][j][0] += r * c0[ni];
            dt[mi][j][1] += r * c1[ni];
            dt[mi][j][2] += r * c2[ni];
            dt[mi][j][3] += r * c3[ni];
          }
        }
#pragma unroll
      for (int o = 1; o < 16; o <<= 1)
#pragma unroll
        for (int mi = 0; mi < 4; ++mi)
#pragma unroll
          for (int j = 0; j < 4; ++j)
#pragma unroll
            for (int q = 0; q < 4; ++q)
              dt[mi][j][q] += __shfl_xor(dt[mi][j][q], o, 64);
      float* lt = (float*)sm;
      if (fr == 0) {
#pragma unroll
        for (int mi = 0; mi < 4; ++mi)
#pragma unroll
          for (int j = 0; j < 4; ++j) {
            int rr = wr + mi * 16 + fq * 4 + j;
#pragma unroll
            for (int q = 0; q < 4; ++q) lt[(rr * 4 + nw) * 4 + q] = dt[mi][j][q];
          }
      }
      __syncthreads();
      if (nw == 0 && fr == 0) {
        float* fd = gp.fout + (size_t)NR * DD;
        float* fw = fd + (size_t)NR * 2;
#pragma unroll
        for (int mi = 0; mi < 4; ++mi)
#pragma unroll
          for (int j = 0; j < 4; ++j) {
            int rr = wr + mi * 16 + fq * 4 + j;
            int row = m0 + rr;
            float T[4];
#pragma unroll
            for (int q = 0; q < 4; ++q)
              T[q] = lt[(rr * 4 + 0) * 4 + q] + lt[(rr * 4 + 1) * 4 + q] +
                     lt[(rr * 4 + 2) * 4 + q] + lt[(rr * 4 + 3) * 4 + q];
            fd[2 * row] = T[0] + gp.p1[0];
            fd[2 * row + 1] = T[1] + gp.p1[1];
            fw[2 * row] = 1.f / (1.f + expf(-(T[2] + gp.p3[0])));
            fw[2 * row + 1] = 1.f / (1.f + expf(-(T[3] + gp.p3[1])));
          }
      }
    }
  }
}

// ---------------- MFMA GEMM, BM=128 BN=384, BK=64 dbuf counted-vmcnt ---------
template <int EPI, int AFP32>
__global__ __launch_bounds__(512, 1) void gemm_k(GP gp) {
  __shared__ __align__(16) __bf16 sm[2 * 32768];
  const int t = threadIdx.x;
  const int w = t >> 6, lane = t & 63;
  const int m0 = blockIdx.x * 128;
  const int fr = lane & 15, fq = lane >> 4;
  const int wr = (w >> 2) * 64, wc = (w & 3) * 96;
  const int K = gp.K;

  const __bf16* aptr[2];
  int aadv[2];
  const __bf16* bptr[6];
#pragma unroll
  for (int j = 0; j < 2; ++j) {
    int rloc = w * 16 + j * 8 + (lane >> 3);
    int cch = (lane & 7) ^ (rloc & 7);
    if constexpr (!AFP32) {
      int ar = gp.idx ? gp.idx[m0 + rloc] : (m0 + rloc);
      if (ar >= 0) { aptr[j] = (const __bf16*)gp.A + (size_t)ar * K + cch * 8; aadv[j] = 64; }
      else { aptr[j] = gp.zpage; aadv[j] = 0; }
    }
  }
#pragma unroll
  for (int j = 0; j < 6; ++j) {
    int rloc = w * 48 + j * 8 + (lane >> 3);
    int cch = (lane & 7) ^ (rloc & 7);
    bptr[j] = gp.WT + (size_t)rloc * K + cch * 8;
  }
  const float* Af = (const float*)gp.A;
  const int Kr = gp.Kr;
  const int NT = K >> 6;

  f32x4 acc[4][6];
  zero_acc(acc);

  auto stageG = [&](int buf) {
    __bf16* As = sm + buf * 32768;
    __bf16* Bs = As + 8192;
#pragma unroll
    for (int j = 0; j < 2; ++j) {
      gl_lds16(aptr[j], &As[(w * 16 + j * 8) * 64]);
      aptr[j] += aadv[j];
    }
#pragma unroll
    for (int j = 0; j < 6; ++j) {
      gl_lds16(bptr[j], &Bs[(w * 48 + j * 8) * 64]);
      bptr[j] += 64;
    }
  };

  auto stageF = [&](int k0) {
    __bf16* As = sm;
    __bf16* Bs = sm + 8192;
#pragma unroll
    for (int j = 0; j < 2; ++j) {
      int rr = (t >> 3) + 64 * j;
      int cc = t & 7;
      int kb = k0 + cc * 8;
      const float* ap = Af + (size_t)(m0 + rr) * Kr + kb;
      bf16x8 h;
      if (kb + 8 <= Kr) {
        f4 v0 = ld4(ap), v1 = ld4(ap + 4);
#pragma unroll
        for (int e = 0; e < 4; ++e) { h[e] = (__bf16)v0[e]; h[4 + e] = (__bf16)v1[e]; }
      } else {
#pragma unroll
        for (int e = 0; e < 8; ++e) h[e] = (kb + e < Kr) ? (__bf16)ap[e] : (__bf16)0.f;
      }
      *reinterpret_cast<bf16x8*>(&As[rr * 64 + ((cc ^ (rr & 7)) << 3)]) = h;
    }
#pragma unroll
    for (int j = 0; j < 6; ++j) {
      gl_lds16(bptr[j], &Bs[(w * 48 + j * 8) * 64]);
      bptr[j] += 64;
    }
  };

  if constexpr (AFP32) {
    for (int tt = 0; tt < NT; ++tt) {
      if (tt) __syncthreads();
      stageF(tt << 6);
      __syncthreads();
      mfma_block(sm, sm + 8192, acc, wr, wc, fr, fq);
    }
  } else {
    stageG(0);
    int buf = 0;
    for (int tt = 0; tt < NT; ++tt) {
      if (tt + 1 < NT) {
        stageG(buf ^ 1);
        asm volatile("s_waitcnt vmcnt(8)" ::: "memory");
      } else {
        asm volatile("s_waitcnt vmcnt(0)" ::: "memory");
      }
      __builtin_amdgcn_s_barrier();
      __builtin_amdgcn_sched_barrier(0);
      mfma_block(sm + buf * 32768, sm + buf * 32768 + 8192, acc, wr, wc, fr, fq);
      __builtin_amdgcn_s_barrier();
      __builtin_amdgcn_sched_barrier(0);
      buf ^= 1;
    }
  }
  epilogue<EPI>(gp, acc, sm, m0, w, lane);
}

// ---- BK=128 GEMM for epilogue-heavy launches: 16 loads/thread per stage -----
template <int EPI, int AFP32>
__global__ __launch_bounds__(512, 1) void gemm_k128(GP gp) {
  __shared__ __align__(16) __bf16 sm[65536];
  const int t = threadIdx.x;
  const int w = t >> 6, lane = t & 63;
  const int m0 = blockIdx.x * 128;
  const int fr = lane & 15, fq = lane >> 4;
  const int wr = (w >> 2) * 64, wc = (w & 3) * 96;
  const int K = gp.K;

  const __bf16* aptr[2];
  int aadv[2];
  const __bf16* bptr[6];
#pragma unroll
  for (int j = 0; j < 2; ++j) {
    int rloc = w * 16 + j * 8 + (lane >> 3);
    int cch = (lane & 7) ^ (rloc & 7);
    if constexpr (!AFP32) {
      int ar = gp.idx ? gp.idx[m0 + rloc] : (m0 + rloc);
      if (ar >= 0) { aptr[j] = (const __bf16*)gp.A + (size_t)ar * K + cch * 8; aadv[j] = 64; }
      else { aptr[j] = gp.zpage; aadv[j] = 0; }
    }
  }
#pragma unroll
  for (int j = 0; j < 6; ++j) {
    int rloc = w * 48 + j * 8 + (lane >> 3);
    int cch = (lane & 7) ^ (rloc & 7);
    bptr[j] = gp.WT + (size_t)rloc * K + cch * 8;
  }
  const float* Af = (const float*)gp.A;
  const int Kr = gp.Kr;
  const int NT = K >> 7;

  f32x4 acc[4][6];
  zero_acc(acc);

  for (int tt = 0; tt < NT; ++tt) {
    if (tt) __syncthreads();
#pragma unroll
    for (int h = 0; h < 2; ++h) {
      __bf16* As = sm + h * 8192;
      __bf16* Bs = sm + 16384 + h * 24576;
      if constexpr (AFP32) {
#pragma unroll
        for (int j = 0; j < 2; ++j) {
          int rr = (t >> 3) + 64 * j;
          int cc = t & 7;
          int kb = (tt << 7) + (h << 6) + cc * 8;
          const float* ap = Af + (size_t)(m0 + rr) * Kr + kb;
          bf16x8 hv;
          if (kb + 8 <= Kr) {
            f4 v0 = ld4(ap), v1 = ld4(ap + 4);
#pragma unroll
            for (int e = 0; e < 4; ++e) { hv[e] = (__bf16)v0[e]; hv[4 + e] = (__bf16)v1[e]; }
          } else {
#pragma unroll
            for (int e = 0; e < 8; ++e) hv[e] = (kb + e < Kr) ? (__bf16)ap[e] : (__bf16)0.f;
          }
          *reinterpret_cast<bf16x8*>(&As[rr * 64 + ((cc ^ (rr & 7)) << 3)]) = hv;
        }
      } else {
#pragma unroll
        for (int j = 0; j < 2; ++j) {
          gl_lds16(aptr[j], &As[(w * 16 + j * 8) * 64]);
          aptr[j] += aadv[j];
        }
      }
#pragma unroll
      for (int j = 0; j < 6; ++j) {
        gl_lds16(bptr[j], &Bs[(w * 48 + j * 8) * 64]);
        bptr[j] += 64;
      }
    }
    __syncthreads();
#pragma unroll
    for (int h = 0; h < 2; ++h)
      mfma_block(sm + h * 8192, sm + 16384 + h * 24576, acc, wr, wc, fr, fq);
  }
  __syncthreads();
  epilogue<EPI>(gp, acc, sm, m0, w, lane);
}

// -------- dual-B GEMM: whole A tile resident in LDS; two B phases -----------
template <int EPIA, int EPIB>
__global__ __launch_bounds__(512, 1) void gemm_dual_k(GP ga, GP gb) {
  __shared__ __align__(16) __bf16 sm[73728];
  const int t = threadIdx.x;
  const int w = t >> 6, lane = t & 63;
  const int m0 = blockIdx.x * 128;
  const int fr = lane & 15, fq = lane >> 4;
  const int wr = (w >> 2) * 64, wc = (w & 3) * 96;
  __bf16* As = sm;
  __bf16* Bs = sm + 49152;

  {
    const __bf16* aptr[2];
#pragma unroll
    for (int j = 0; j < 2; ++j) {
      int rloc = w * 16 + j * 8 + (lane >> 3);
      int cch = (lane & 7) ^ (rloc & 7);
      aptr[j] = (const __bf16*)ga.A + (size_t)(m0 + rloc) * DD + cch * 8;
    }
#pragma unroll
    for (int tt = 0; tt < 6; ++tt)
#pragma unroll
      for (int j = 0; j < 2; ++j) {
        gl_lds16(aptr[j], &As[tt * 8192 + (w * 16 + j * 8) * 64]);
        aptr[j] += 64;
      }
  }

  f32x4 acc[4][6];
  auto run_phase = [&](const GP& gp) {
    const __bf16* bptr[6];
#pragma unroll
    for (int j = 0; j < 6; ++j) {
      int rloc = w * 48 + j * 8 + (lane >> 3);
      int cch = (lane & 7) ^ (rloc & 7);
      bptr[j] = gp.WT + (size_t)rloc * DD + cch * 8;
    }
    for (int tt = 0; tt < 6; ++tt) {
      __syncthreads();
#pragma unroll
      for (int j = 0; j < 6; ++j) {
        gl_lds16(bptr[j], &Bs[(w * 48 + j * 8) * 64]);
        bptr[j] += 64;
      }
      asm volatile("s_waitcnt vmcnt(0)" ::: "memory");
      __builtin_amdgcn_s_barrier();
      __builtin_amdgcn_sched_barrier(0);
      mfma_block(As + tt * 8192, Bs, acc, wr, wc, fr, fq);
    }
  };

  zero_acc(acc);
  run_phase(ga);
  epilogue<EPIA>(ga, acc, sm + 49152 + 24576, m0, w, lane);
  zero_acc(acc);
  run_phase(gb);
  epilogue<EPIB>(gb, acc, sm + 49152 + 24576, m0, w, lane);
}

// ---------------- fused addgather + LayerNorm ----------------
__global__ __launch_bounds__(256) void ln_ag_k(const __bf16* __restrict__ X,
                                               const __bf16* __restrict__ z,
                                               const int* __restrict__ gid,
                                               const float* __restrict__ g,
                                               const float* __restrict__ b,
                                               __bf16* __restrict__ out) {
  int w = threadIdx.x >> 6, lane = threadIdx.x & 63;
  int s = lane & 15, qq = lane >> 4;
  int row = blockIdx.x * 16 + w * 4 + qq;
  int gr = gid[row];
  size_t base = (size_t)row * DD;
  size_t zbase = (size_t)gr * DD;
  float v[24];
#pragma unroll
  for (int i = 0; i < 3; ++i) {
    int col = (s + 16 * i) * 8;
    bf16x8 h = ld8h(X + base + col);
    bf16x8 zz = ld8h(z + zbase + col);
#pragma unroll
    for (int e = 0; e < 8; ++e) v[i * 8 + e] = (float)h[e] + (float)zz[e];
  }
  float sm = 0.f;
#pragma unroll
  for (int i = 0; i < 24; ++i) sm += v[i];
  sm = gred16(sm);
  float mean = sm * (1.f / 384.f);
  float qs = 0.f;
#pragma unroll
  for (int i = 0; i < 24; ++i) { float d = v[i] - mean; qs += d * d; }
  qs = gred16(qs);
  float rs = rsqrtf(qs * (1.f / 384.f) + 1e-3f);
#pragma unroll
  for (int i = 0; i < 3; ++i) {
    int col = (s + 16 * i) * 8;
    f4 g0 = ld4(g + col), g1 = ld4(g + col + 4);
    f4 b0 = ld4(b + col), b1 = ld4(b + col + 4);
    bf16x8 o;
#pragma unroll
    for (int e = 0; e < 4; ++e) {
      o[e] = (__bf16)((v[i * 8 + e] - mean) * rs * g0[e] + b0[e]);
      o[4 + e] = (__bf16)((v[i * 8 + 4 + e] - mean) * rs * g1[e] + b1[e]);
    }
    st8h(out + base + col, o);
  }
}

// ---------------- segment rowlist build ----------------
__global__ __launch_bounds__(256) void hist2_k(const int* __restrict__ ukk,
                                               const int* __restrict__ ujk,
                                               int* __restrict__ ckk,
                                               int* __restrict__ cij) {
  int i = blockIdx.x * 256 + threadIdx.x;
  atomicAdd(&ckk[ukk[i]], 1);
  atomicAdd(&cij[ujk[i]], 1);
}

__device__ inline void scan_body(const int* cnt, int* off, int* curb, int G, int* ls) {
  int t = threadIdx.x;
  int per = G / 256;
  int base = t * per;
  int s = 0;
  for (int i = 0; i < per; ++i) s += cnt[base + i];
  ls[t] = s;
  __syncthreads();
  for (int o = 1; o < 256; o <<= 1) {
    int v = (t >= o) ? ls[t - o] : 0;
    __syncthreads();
    ls[t] += v;
    __syncthreads();
  }
  int run = (t == 0) ? 0 : ls[t - 1];
  for (int i = 0; i < per; ++i) {
    off[base + i] = run;
    run += cnt[base + i];
    curb[base + i] = 0;
  }
  if (t == 255) off[G] = run;
}

__global__ __launch_bounds__(256) void scan2_k(const int* ckk, int* okk, int* qkk,
                                               const int* cij, int* oij, int* qij) {
  __shared__ int ls[256];
  if (blockIdx.x == 0) scan_body(ckk, okk, qkk, 4096, ls);
  else scan_body(cij, oij, qij, 512, ls);
}

__global__ __launch_bounds__(256) void scatter2_k(const int* __restrict__ ukk,
                                                  const int* __restrict__ ujk,
                                                  const int* __restrict__ okk,
                                                  int* __restrict__ qkk,
                                                  int* __restrict__ rkk,
                                                  const int* __restrict__ oij,
                                                  int* __restrict__ qij,
                                                  int* __restrict__ rij) {
  int i = blockIdx.x * 256 + threadIdx.x;
  int g1 = ukk[i];
  rkk[okk[g1] + atomicAdd(&qkk[g1], 1)] = i;
  int g2 = ujk[i];
  rij[oij[g2] + atomicAdd(&qij[g2], 1)] = i;
}

// one block per group, 384 threads = one per column
__global__ __launch_bounds__(384) void segagg_k(const __bf16* __restrict__ L,
                                                const __bf16* __restrict__ Ft,
                                                const int* __restrict__ rows,
                                                const int* __restrict__ off,
                                                float* __restrict__ yb) {
  int g = blockIdx.x;
  int c = threadIdx.x;
  int s = off[g], e = off[g + 1];
  float mx = -3.0e38f;
  for (int p = s; p < e; ++p) {
    int r = rows[p];
    mx = fmaxf(mx, (float)L[(size_t)r * DD + c]);
  }
  float num = 0.f, den = 0.f;
  for (int p = s; p < e; ++p) {
    int r = rows[p];
    float lv = (float)L[(size_t)r * DD + c];
    float fv = (float)Ft[(size_t)r * DD + c];
    float ev = expf(lv - mx);
    den += ev;
    num += fv * ev;
  }
  yb[(size_t)g * DD + c] = num / (den + 1e-12f);
}

__global__ __launch_bounds__(256) void addgather_k(__bf16* __restrict__ X,
                                                   const __bf16* __restrict__ z,
                                                   const int* __restrict__ gid) {
  int i = blockIdx.x * 256 + threadIdx.x;
  int row = i / 48, c = (i - row * 48) * 8;
  int g = gid[row];
  size_t lo = (size_t)row * DD + c;
  bf16x8 a = ld8h(X + lo);
  bf16x8 zz = ld8h(z + (size_t)g * DD + c);
  bf16x8 o;
#pragma unroll
  for (int e = 0; e < 8; ++e) o[e] = (__bf16)((float)a[e] + (float)zz[e]);
  st8h(X + lo, o);
}

extern "C" void kernel_launch(void* const* d_in, const int* in_sizes, int n_in,
                              void* d_out, int out_size, void* d_ws, size_t ws_size,
                              hipStream_t stream) {
  const float* in_net = (const float*)d_in[0];
  const float* in_inp = (const float*)d_in[1];
  const float* in_corr = (const float*)d_in[2];
  const int* nix = (const int*)d_in[3];
  const int* njx = (const int*)d_in[4];
  const int* ukk = (const int*)d_in[5];
  const int* ujk = (const int*)d_in[6];
  auto F = [&](int i) { return (const float*)d_in[i]; };

  constexpr size_t MiB = 1024 * 1024;
  constexpr size_t SZ_ACT = (size_t)NR * DD * 2;
  char* ws = (char*)d_ws;
  __bf16* T2b = (__bf16*)(ws);
  __bf16* Fb = (__bf16*)(ws + SZ_ACT);
  __bf16* zb = (__bf16*)(ws + 2 * SZ_ACT);         // 3 MiB
  float* yb = (float*)(ws + 2 * SZ_ACT + 3 * MiB); // 6 MiB
  __bf16* T1b = (__bf16*)(ws + 60 * MiB);          // 24 MiB
  char* p = ws + 84 * MiB;
  int* rows_kk = (int*)p; p += (size_t)NR * 4;
  int* rows_ij = (int*)p; p += (size_t)NR * 4;
  int* off_kk = (int*)p; p += 8192 * 4;
  int* off_ij = (int*)p; p += 1024 * 4;
  int* cnt_kk = (int*)p; p += 4096 * 4;
  int* cnt_ij = (int*)p; p += 512 * 4;
  int* curb_kk = (int*)p; p += 4096 * 4;
  int* curb_ij = (int*)p; p += 512 * 4;
  __bf16* wt_all = (__bf16*)p; p += (size_t)18 * DD * DD * 2;
  __bf16* wt_corr1 = (__bf16*)p; p += (size_t)DD * CDMP * 2;
  __bf16* zpage = (__bf16*)p;

  const int widx[18] = {17, 19, 21, 23, 25, 27, 29, 31, 33, 35, 39, 41, 43, 47, 49, 51, 9, 13};
  WPtrs P;
  for (int i = 0; i < 18; ++i) P.w[i] = F(widx[i]);
  P.w[18] = F(7);
  auto WTp = [&](int i) { return wt_all + (size_t)i * DD * DD; };

  hipMemsetAsync(zpage, 0, 256, stream);
  hipMemsetAsync(cnt_kk, 0, 4096 * 4, stream);
  hipMemsetAsync(cnt_ij, 0, 512 * 4, stream);
  trans_all_k<<<dim3(1344, 19), 256, 0, stream>>>(P, wt_all);
  hist2_k<<<NR / 256, 256, 0, stream>>>(ukk, ujk, cnt_kk, cnt_ij);
  scan2_k<<<2, 256, 0, stream>>>(cnt_kk, off_kk, curb_kk, cnt_ij, off_ij, curb_ij);
  scatter2_k<<<NR / 256, 256, 0, stream>>>(ukk, ujk, off_kk, curb_kk, rows_kk,
                                           off_ij, curb_ij, rows_ij);

  auto G = [&](int epi, const void* A, const __bf16* WT, const float* bias,
               __bf16* OUT, const __bf16* XRES, const __bf16* GIN,
               const float* p0, const float* p1, const float* p2, const float* p3,
               float* fout, const float* n32, const float* i32,
               const int* idx, int M, int K, int Kr) {
    GP gp{A, WT, bias, OUT, XRES, GIN, p0, p1, p2, p3, fout, n32, i32, idx, zpage, M, K, Kr};
    dim3 g(M / 128), b(512);
    switch (epi) {
      case 0: gemm_k<0, 0><<<g, b, 0, stream>>>(gp); break;
      case 1: gemm_k<1, 0><<<g, b, 0, stream>>>(gp); break;
      case 2: gemm_k<2, 0><<<g, b, 0, stream>>>(gp); break;
      case 4: gemm_k128<4, 0><<<g, b, 0, stream>>>(gp); break;
      case 5: gemm_k128<5, 0><<<g, b, 0, stream>>>(gp); break;
      case 6: gemm_k128<6, 0><<<g, b, 0, stream>>>(gp); break;
      case 7: gemm_k128<7, 0><<<g, b, 0, stream>>>(gp); break;
      case 8: gemm_k<0, 1><<<g, b, 0, stream>>>(gp); break;   // AFP32 store (small M)
      case 9: gemm_k128<1, 1><<<g, b, 0, stream>>>(gp); break; // AFP32 relu (corr)
    }
  };
  auto GS = [&](int epi, const void* A, const __bf16* WT, const float* bias,
                __bf16* OUT, const int* idx, int M, int K) {
    G(epi, A, WT, bias, OUT, nullptr, nullptr, nullptr, nullptr, nullptr, nullptr,
      nullptr, nullptr, nullptr, idx, M, K, K);
  };
  auto GD = [&](const void* A, const __bf16* WTa, const float* ba, __bf16* Oa,
                const __bf16* WTb, const float* bb, __bf16* Ob, int epib) {
    GP ga{A, WTa, ba, Oa, nullptr, nullptr, nullptr, nullptr, nullptr, nullptr,
          nullptr, nullptr, nullptr, nullptr, zpage, NR, DD, DD};
    GP gb{A, WTb, bb, Ob, nullptr, nullptr, nullptr, nullptr, nullptr, nullptr,
          nullptr, nullptr, nullptr, nullptr, zpage, NR, DD, DD};
    dim3 g(NR / 128), b(512);
    if (epib == 0) gemm_dual_k<0, 0><<<g, b, 0, stream>>>(ga, gb);
    else gemm_dual_k<0, 1><<<g, b, 0, stream>>>(ga, gb);
  };

  const int SEGB = NR * 48 / 256;

  // corr encoder (fp32 A read in-GEMM; Kr = 882 real row stride; K=896=7*128)
  G(9, in_corr, wt_corr1, F(8), T1b, nullptr, nullptr, nullptr, nullptr, nullptr,
    nullptr, nullptr, nullptr, nullptr, nullptr, NR, CDMP, CDM);       // relu(h1)
  G(4, T1b, WTp(16), F(10), T2b, nullptr, nullptr, F(11), F(12), nullptr, nullptr,
    nullptr, nullptr, nullptr, nullptr, NR, DD, DD);                   // relu(LN(h2))
  G(5, T2b, WTp(17), F(14), T1b, nullptr, nullptr, F(15), F(16), nullptr, nullptr,
    nullptr, in_net, in_inp, nullptr, NR, DD, DD);                     // T1b = net2
  // c1
  GS(1, T1b, WTp(0), F(18), T2b, nix, NR, DD);
  GS(2, T2b, WTp(1), F(20), T1b, nullptr, NR, DD);                     // net3
  // c2
  GS(1, T1b, WTp(2), F(22), T2b, njx, NR, DD);
  GS(2, T2b, WTp(3), F(24), T1b, nullptr, NR, DD);                     // net4
  // kk soft-agg: logits+feats in one dual launch
  GD(T1b, WTp(5), F(28), T2b, WTp(4), F(26), Fb, 0);
  segagg_k<<<4096, 384, 0, stream>>>(T2b, Fb, rows_kk, off_kk, yb);
  GS(8, yb, WTp(6), F(30), zb, nullptr, 4096, DD);
  addgather_k<<<SEGB, 256, 0, stream>>>(T1b, zb, ukk);                 // net5
  // ij soft-agg
  GD(T1b, WTp(8), F(34), T2b, WTp(7), F(32), Fb, 0);
  segagg_k<<<512, 384, 0, stream>>>(T2b, Fb, rows_ij, off_ij, yb);
  GS(8, yb, WTp(9), F(36), zb, nullptr, 512, DD);
  ln_ag_k<<<NR / 16, 256, 0, stream>>>(T1b, zb, ujk, F(37), F(38), T2b);  // x1
  // gated residual 1: gate + relu-hidden dual, then LN2-fused consumer
  GD(T2b, WTp(10), F(40), Fb, WTp(11), F(42), T1b, 1);
  G(6, T1b, WTp(12), F(44), T2b, T2b, Fb, F(45), F(46), nullptr, nullptr,
    nullptr, nullptr, nullptr, nullptr, NR, DD, DD);                   // x2 = LN2(net7)
  // gated residual 2 + final heads
  GD(T2b, WTp(13), F(48), Fb, WTp(14), F(50), T1b, 1);
  G(7, T1b, WTp(15), F(52), nullptr, T2b, Fb, F(53), F(54), F(55), F(56),
    (float*)d_out, nullptr, nullptr, nullptr, NR, DD, DD);             // out
}

// Round 19
// 600.460 us; speedup vs baseline: 1.0915x; 1.0359x over previous
//
#include <hip/hip_runtime.h>
#include <hip/hip_bf16.h>
#include <math.h>

#define NR 32768
#define DD 384
#define CDM 882
#define CDMP 896

typedef float f4 __attribute__((ext_vector_type(4)));
typedef float f32x4 __attribute__((ext_vector_type(4)));
typedef __bf16 bf16x8 __attribute__((ext_vector_type(8)));

__device__ inline f4 ld4(const float* p) { f4 v; __builtin_memcpy(&v, p, 16); return v; }
__device__ inline bf16x8 ld8h(const __bf16* p) { bf16x8 v; __builtin_memcpy(&v, p, 16); return v; }
__device__ inline void st8h(__bf16* p, bf16x8 v) { __builtin_memcpy(p, &v, 16); }

__device__ inline void gl_lds16(const void* g, void* l) {
  __builtin_amdgcn_global_load_lds(
      (const __attribute__((address_space(1))) void*)g,
      (__attribute__((address_space(3))) void*)l, 16, 0, 0);
}

__device__ inline float gred16(float v) {
#pragma unroll
  for (int o = 1; o < 16; o <<= 1) v += __shfl_xor(v, o, 64);
  return v;
}

// ---------------- weight transposes (18 square + corr in one launch) --------
struct WPtrs { const float* w[19]; };

__global__ __launch_bounds__(256) void trans_all_k(WPtrs P, __bf16* __restrict__ dst) {
  int wi = blockIdx.y;
  const float* W = P.w[wi];
  int i = blockIdx.x * 256 + threadIdx.x;
  if (wi < 18) {
    if (i >= DD * DD) return;
    int n = i / DD, k = i - n * DD;
    dst[(size_t)wi * DD * DD + i] = (__bf16)W[(size_t)k * DD + n];
  } else {
    if (i >= DD * CDMP) return;
    int n = i / CDMP, k = i - n * CDMP;
    dst[(size_t)18 * DD * DD + i] = (k < CDM) ? (__bf16)W[(size_t)k * DD + n] : (__bf16)0.f;
  }
}

// ---------------- GEMM params ----------------
struct GP {
  const void* A; const __bf16* WT; const float* bias; __bf16* OUT;
  const __bf16* XRES; const __bf16* GIN;
  const float* p0; const float* p1; const float* p2; const float* p3;
  float* fout; const float* net32; const float* inp32;
  const int* idx; const __bf16* zpage; int M; int K; int Kr;
};

__device__ __forceinline__ void mfma_block(const __bf16* As, const __bf16* Bs,
                                           f32x4 (&acc)[4][6], int wr, int wc,
                                           int fr, int fq) {
#pragma unroll
  for (int kk2 = 0; kk2 < 2; ++kk2) {
    bf16x8 af[4];
    bf16x8 bv[6];
#pragma unroll
    for (int mi = 0; mi < 4; ++mi) {
      int rr = wr + mi * 16 + fr;
      af[mi] = *reinterpret_cast<const bf16x8*>(
          &As[rr * 64 + (((fq + kk2 * 4) ^ (rr & 7)) << 3)]);
    }
#pragma unroll
    for (int ni = 0; ni < 6; ++ni) {
      int rr = wc + ni * 16 + fr;
      bv[ni] = *reinterpret_cast<const bf16x8*>(
          &Bs[rr * 64 + (((fq + kk2 * 4) ^ (rr & 7)) << 3)]);
    }
#pragma unroll
    for (int mi = 0; mi < 4; ++mi)
#pragma unroll
      for (int ni = 0; ni < 6; ++ni)
        acc[mi][ni] = __builtin_amdgcn_mfma_f32_16x16x32_bf16(af[mi], bv[ni],
                                                              acc[mi][ni], 0, 0, 0);
  }
}

__device__ __forceinline__ void zero_acc(f32x4 (&acc)[4][6]) {
#pragma unroll
  for (int a = 0; a < 4; ++a)
#pragma unroll
    for (int b = 0; b < 6; ++b)
#pragma unroll
      for (int j = 0; j < 4; ++j) acc[a][b][j] = 0.f;
}

// ---------- epilogue (BM=128, BN=384, 8 waves, acc 4x6) ----------
// EPI: 0 store, 1 relu, 2 OUT+=v, 4 relu(LN(v)), 5 LN(net+inp+v),
//      6 x=LN(XRES+sig(GIN)*v), 7 final: net9=XRES+sig(GIN)*v -> fp32 out + heads
template <int EPI>
__device__ __forceinline__ void epilogue(const GP& gp, f32x4 (&acc)[4][6],
                                         __bf16* sm, int m0, int w, int lane) {
  const int fr = lane & 15, fq = lane >> 4;
  const int wr = (w >> 2) * 64, wc = (w & 3) * 96;
  const int nw = w & 3;
  float bcol[6];
#pragma unroll
  for (int ni = 0; ni < 6; ++ni) bcol[ni] = gp.bias[wc + ni * 16 + fr];
#pragma unroll
  for (int mi = 0; mi < 4; ++mi)
#pragma unroll
    for (int ni = 0; ni < 6; ++ni)
#pragma unroll
      for (int j = 0; j < 4; ++j) acc[mi][ni][j] += bcol[ni];

  if constexpr (EPI <= 2) {
#pragma unroll
    for (int mi = 0; mi < 4; ++mi)
#pragma unroll
      for (int ni = 0; ni < 6; ++ni) {
        int col = wc + ni * 16 + fr;
#pragma unroll
        for (int j = 0; j < 4; ++j) {
          int row = m0 + wr + mi * 16 + fq * 4 + j;
          size_t o = (size_t)row * DD + col;
          float v = acc[mi][ni][j];
          if constexpr (EPI == 0) gp.OUT[o] = (__bf16)v;
          else if constexpr (EPI == 1) gp.OUT[o] = (__bf16)fmaxf(v, 0.f);
          else gp.OUT[o] = (__bf16)((float)gp.OUT[o] + v);
        }
      }
  } else {
    if constexpr (EPI == 5) {
#pragma unroll
      for (int mi = 0; mi < 4; ++mi)
#pragma unroll
        for (int ni = 0; ni < 6; ++ni) {
          int col = wc + ni * 16 + fr;
#pragma unroll
          for (int j = 0; j < 4; ++j) {
            int row = m0 + wr + mi * 16 + fq * 4 + j;
            size_t o = (size_t)row * DD + col;
            acc[mi][ni][j] += gp.net32[o] + gp.inp32[o];
          }
        }
    }
    if constexpr (EPI == 6 || EPI == 7) {
#pragma unroll
      for (int mi = 0; mi < 4; ++mi)
#pragma unroll
        for (int ni = 0; ni < 6; ++ni) {
          int col = wc + ni * 16 + fr;
#pragma unroll
          for (int j = 0; j < 4; ++j) {
            int row = m0 + wr + mi * 16 + fq * 4 + j;
            size_t o = (size_t)row * DD + col;
            float gl = (float)gp.GIN[o];
            float sg = 1.f / (1.f + expf(-gl));
            acc[mi][ni][j] = (float)gp.XRES[o] + sg * acc[mi][ni][j];
          }
        }
    }
    __syncthreads();
    if constexpr (EPI != 7) {
      float s1[4][4], s2[4][4];
#pragma unroll
      for (int mi = 0; mi < 4; ++mi)
#pragma unroll
        for (int j = 0; j < 4; ++j) { s1[mi][j] = 0.f; s2[mi][j] = 0.f; }
#pragma unroll
      for (int mi = 0; mi < 4; ++mi)
#pragma unroll
        for (int ni = 0; ni < 6; ++ni)
#pragma unroll
          for (int j = 0; j < 4; ++j) {
            float v = acc[mi][ni][j];
            s1[mi][j] += v;
            s2[mi][j] += v * v;
          }
#pragma unroll
      for (int o = 1; o < 16; o <<= 1)
#pragma unroll
        for (int mi = 0; mi < 4; ++mi)
#pragma unroll
          for (int j = 0; j < 4; ++j) {
            s1[mi][j] += __shfl_xor(s1[mi][j], o, 64);
            s2[mi][j] += __shfl_xor(s2[mi][j], o, 64);
          }
      float* lsum = (float*)sm;
      float* lsq = lsum + 512;
      if (fr == 0) {
#pragma unroll
        for (int mi = 0; mi < 4; ++mi)
#pragma unroll
          for (int j = 0; j < 4; ++j) {
            int rr = wr + mi * 16 + fq * 4 + j;
            lsum[rr * 4 + nw] = s1[mi][j];
            lsq[rr * 4 + nw] = s2[mi][j];
          }
      }
      __syncthreads();
      float mn[4][4], rs[4][4];
#pragma unroll
      for (int mi = 0; mi < 4; ++mi)
#pragma unroll
        for (int j = 0; j < 4; ++j) {
          int rr = wr + mi * 16 + fq * 4 + j;
          float S1 = lsum[rr * 4] + lsum[rr * 4 + 1] + lsum[rr * 4 + 2] + lsum[rr * 4 + 3];
          float S2 = lsq[rr * 4] + lsq[rr * 4 + 1] + lsq[rr * 4 + 2] + lsq[rr * 4 + 3];
          float m = S1 * (1.f / 384.f);
          float va = S2 * (1.f / 384.f) - m * m;
          mn[mi][j] = m;
          rs[mi][j] = rsqrtf(va + 1e-3f);
        }
#pragma unroll
      for (int ni = 0; ni < 6; ++ni) {
        int col = wc + ni * 16 + fr;
        float gg = gp.p0[col], bb = gp.p1[col];
#pragma unroll
        for (int mi = 0; mi < 4; ++mi)
#pragma unroll
          for (int j = 0; j < 4; ++j) {
            int row = m0 + wr + mi * 16 + fq * 4 + j;
            float y = (acc[mi][ni][j] - mn[mi][j]) * rs[mi][j] * gg + bb;
            if constexpr (EPI == 4) y = fmaxf(y, 0.f);
            gp.OUT[(size_t)row * DD + col] = (__bf16)y;
          }
      }
    } else {
      float c0[6], c1[6], c2[6], c3[6];
#pragma unroll
      for (int ni = 0; ni < 6; ++ni) {
        int col = wc + ni * 16 + fr;
        c0[ni] = gp.p0[2 * col];
        c1[ni] = gp.p0[2 * col + 1];
        c2[ni] = gp.p2[2 * col];
        c3[ni] = gp.p2[2 * col + 1];
      }
      float dt[4][4][4];
#pragma unroll
      for (int mi = 0; mi < 4; ++mi)
#pragma unroll
        for (int j = 0; j < 4; ++j)
#pragma unroll
          for (int q = 0; q < 4; ++q) dt[mi][j][q] = 0.f;
#pragma unroll
      for (int mi = 0; mi < 4; ++mi)
#pragma unroll
        for (int ni = 0; ni < 6; ++ni) {
          int col = wc + ni * 16 + fr;
#pragma unroll
          for (int j = 0; j < 4; ++j) {
            int row = m0 + wr + mi * 16 + fq * 4 + j;
            float v = acc[mi][ni][j];
            gp.fout[(size_t)row * DD + col] = v;
            float r = fmaxf(v, 0.f);
            dt[mi][j][0] += r * c0[ni];
            dt[mi][j][1] += r * c1[ni];
            dt[mi][j][2] += r * c2[ni];
            dt[mi][j][3] += r * c3[ni];
          }
        }
#pragma unroll
      for (int o = 1; o < 16; o <<= 1)
#pragma unroll
        for (int mi = 0; mi < 4; ++mi)
#pragma unroll
          for (int j = 0; j < 4; ++j)
#pragma unroll
            for (int q = 0; q < 4; ++q)
              dt[mi][j][q] += __shfl_xor(dt[mi][j][q], o, 64);
      float* lt = (float*)sm;
      if (fr == 0) {
#pragma unroll
        for (int mi = 0; mi < 4; ++mi)
#pragma unroll
          for (int j = 0; j < 4; ++j) {
            int rr = wr + mi * 16 + fq * 4 + j;
#pragma unroll
            for (int q = 0; q < 4; ++q) lt[(rr * 4 + nw) * 4 + q] = dt[mi][j][q];
          }
      }
      __syncthreads();
      if (nw == 0 && fr == 0) {
        float* fd = gp.fout + (size_t)NR * DD;
        float* fw = fd + (size_t)NR * 2;
#pragma unroll
        for (int mi = 0; mi < 4; ++mi)
#pragma unroll
          for (int j = 0; j < 4; ++j) {
            int rr = wr + mi * 16 + fq * 4 + j;
            int row = m0 + rr;
            float T[4];
#pragma unroll
            for (int q = 0; q < 4; ++q)
              T[q] = lt[(rr * 4 + 0) * 4 + q] + lt[(rr * 4 + 1) * 4 + q] +
                     lt[(rr * 4 + 2) * 4 + q] + lt[(rr * 4 + 3) * 4 + q];
            fd[2 * row] = T[0] + gp.p1[0];
            fd[2 * row + 1] = T[1] + gp.p1[1];
            fw[2 * row] = 1.f / (1.f + expf(-(T[2] + gp.p3[0])));
            fw[2 * row + 1] = 1.f / (1.f + expf(-(T[3] + gp.p3[1])));
          }
      }
    }
  }
}

// ---------------- MFMA GEMM, BM=128 BN=384 (dbuf counted-vmcnt) --------------
template <int EPI, int AFP32>
__global__ __launch_bounds__(512, 1) void gemm_k(GP gp) {
  __shared__ __align__(16) __bf16 sm[2 * 32768];
  const int t = threadIdx.x;
  const int w = t >> 6, lane = t & 63;
  const int m0 = blockIdx.x * 128;
  const int fr = lane & 15, fq = lane >> 4;
  const int wr = (w >> 2) * 64, wc = (w & 3) * 96;
  const int K = gp.K;

  const __bf16* aptr[2];
  int aadv[2];
  const __bf16* bptr[6];
#pragma unroll
  for (int j = 0; j < 2; ++j) {
    int rloc = w * 16 + j * 8 + (lane >> 3);
    int cch = (lane & 7) ^ (rloc & 7);
    if constexpr (!AFP32) {
      int ar = gp.idx ? gp.idx[m0 + rloc] : (m0 + rloc);
      if (ar >= 0) { aptr[j] = (const __bf16*)gp.A + (size_t)ar * K + cch * 8; aadv[j] = 64; }
      else { aptr[j] = gp.zpage; aadv[j] = 0; }
    }
  }
#pragma unroll
  for (int j = 0; j < 6; ++j) {
    int rloc = w * 48 + j * 8 + (lane >> 3);
    int cch = (lane & 7) ^ (rloc & 7);
    bptr[j] = gp.WT + (size_t)rloc * K + cch * 8;
  }
  const float* Af = (const float*)gp.A;
  const int Kr = gp.Kr;
  const int NT = K >> 6;

  f32x4 acc[4][6];
  zero_acc(acc);

  auto stageG = [&](int buf) {
    __bf16* As = sm + buf * 32768;
    __bf16* Bs = As + 8192;
#pragma unroll
    for (int j = 0; j < 2; ++j) {
      gl_lds16(aptr[j], &As[(w * 16 + j * 8) * 64]);
      aptr[j] += aadv[j];
    }
#pragma unroll
    for (int j = 0; j < 6; ++j) {
      gl_lds16(bptr[j], &Bs[(w * 48 + j * 8) * 64]);
      bptr[j] += 64;
    }
  };

  auto stageF = [&](int k0) {  // fp32 A, row stride Kr, zero-pad k >= Kr
    __bf16* As = sm;
    __bf16* Bs = sm + 8192;
#pragma unroll
    for (int j = 0; j < 2; ++j) {
      int rr = (t >> 3) + 64 * j;
      int cc = t & 7;
      int kb = k0 + cc * 8;
      const float* ap = Af + (size_t)(m0 + rr) * Kr + kb;
      bf16x8 h;
      if (kb + 8 <= Kr) {
        f4 v0 = ld4(ap), v1 = ld4(ap + 4);
#pragma unroll
        for (int e = 0; e < 4; ++e) { h[e] = (__bf16)v0[e]; h[4 + e] = (__bf16)v1[e]; }
      } else {
#pragma unroll
        for (int e = 0; e < 8; ++e) h[e] = (kb + e < Kr) ? (__bf16)ap[e] : (__bf16)0.f;
      }
      *reinterpret_cast<bf16x8*>(&As[rr * 64 + ((cc ^ (rr & 7)) << 3)]) = h;
    }
#pragma unroll
    for (int j = 0; j < 6; ++j) {
      gl_lds16(bptr[j], &Bs[(w * 48 + j * 8) * 64]);
      bptr[j] += 64;
    }
  };

  if constexpr (AFP32) {
    for (int tt = 0; tt < NT; ++tt) {
      if (tt) __syncthreads();
      stageF(tt << 6);
      __syncthreads();
      mfma_block(sm, sm + 8192, acc, wr, wc, fr, fq);
    }
  } else {
    stageG(0);
    int buf = 0;
    for (int tt = 0; tt < NT; ++tt) {
      if (tt + 1 < NT) {
        stageG(buf ^ 1);
        asm volatile("s_waitcnt vmcnt(8)" ::: "memory");
      } else {
        asm volatile("s_waitcnt vmcnt(0)" ::: "memory");
      }
      __builtin_amdgcn_s_barrier();
      __builtin_amdgcn_sched_barrier(0);
      mfma_block(sm + buf * 32768, sm + buf * 32768 + 8192, acc, wr, wc, fr, fq);
      __builtin_amdgcn_s_barrier();
      __builtin_amdgcn_sched_barrier(0);
      buf ^= 1;
    }
  }
  epilogue<EPI>(gp, acc, sm, m0, w, lane);
}

// -------- dual-B GEMM: whole A tile resident in LDS; two B phases -----------
// LDS: A 96 KB ([6][128][64] swizzled) + B 48 KB = 144 KB. grid = M/128.
template <int EPIA, int EPIB>
__global__ __launch_bounds__(512, 1) void gemm_dual_k(GP ga, GP gb) {
  __shared__ __align__(16) __bf16 sm[73728];
  const int t = threadIdx.x;
  const int w = t >> 6, lane = t & 63;
  const int m0 = blockIdx.x * 128;
  const int fr = lane & 15, fq = lane >> 4;
  const int wr = (w >> 2) * 64, wc = (w & 3) * 96;
  __bf16* As = sm;
  __bf16* Bs = sm + 49152;

  // stage entire A (6 K-tiles, 12 gl_lds16 per thread)
  {
    const __bf16* aptr[2];
#pragma unroll
    for (int j = 0; j < 2; ++j) {
      int rloc = w * 16 + j * 8 + (lane >> 3);
      int cch = (lane & 7) ^ (rloc & 7);
      aptr[j] = (const __bf16*)ga.A + (size_t)(m0 + rloc) * DD + cch * 8;
    }
#pragma unroll
    for (int tt = 0; tt < 6; ++tt)
#pragma unroll
      for (int j = 0; j < 2; ++j) {
        gl_lds16(aptr[j], &As[tt * 8192 + (w * 16 + j * 8) * 64]);
        aptr[j] += 64;
      }
  }

  f32x4 acc[4][6];
  auto run_phase = [&](const GP& gp) {
    const __bf16* bptr[6];
#pragma unroll
    for (int j = 0; j < 6; ++j) {
      int rloc = w * 48 + j * 8 + (lane >> 3);
      int cch = (lane & 7) ^ (rloc & 7);
      bptr[j] = gp.WT + (size_t)rloc * DD + cch * 8;
    }
    for (int tt = 0; tt < 6; ++tt) {
      __syncthreads();  // Bs free (prev compute / prev phase done)
#pragma unroll
      for (int j = 0; j < 6; ++j) {
        gl_lds16(bptr[j], &Bs[(w * 48 + j * 8) * 64]);
        bptr[j] += 64;
      }
      asm volatile("s_waitcnt vmcnt(0)" ::: "memory");
      __builtin_amdgcn_s_barrier();
      __builtin_amdgcn_sched_barrier(0);
      mfma_block(As + tt * 8192, Bs, acc, wr, wc, fr, fq);
    }
  };

  zero_acc(acc);
  run_phase(ga);
  epilogue<EPIA>(ga, acc, sm + 49152 + 24576, m0, w, lane);  // sm arg unused (EPI<=1)
  zero_acc(acc);
  run_phase(gb);
  epilogue<EPIB>(gb, acc, sm + 49152 + 24576, m0, w, lane);
}

// ---------------- fused addgather + LayerNorm ----------------
__global__ __launch_bounds__(256) void ln_ag_k(const __bf16* __restrict__ X,
                                               const __bf16* __restrict__ z,
                                               const int* __restrict__ gid,
                                               const float* __restrict__ g,
                                               const float* __restrict__ b,
                                               __bf16* __restrict__ out) {
  int w = threadIdx.x >> 6, lane = threadIdx.x & 63;
  int s = lane & 15, qq = lane >> 4;
  int row = blockIdx.x * 16 + w * 4 + qq;
  int gr = gid[row];
  size_t base = (size_t)row * DD;
  size_t zbase = (size_t)gr * DD;
  float v[24];
#pragma unroll
  for (int i = 0; i < 3; ++i) {
    int col = (s + 16 * i) * 8;
    bf16x8 h = ld8h(X + base + col);
    bf16x8 zz = ld8h(z + zbase + col);
#pragma unroll
    for (int e = 0; e < 8; ++e) v[i * 8 + e] = (float)h[e] + (float)zz[e];
  }
  float sm = 0.f;
#pragma unroll
  for (int i = 0; i < 24; ++i) sm += v[i];
  sm = gred16(sm);
  float mean = sm * (1.f / 384.f);
  float qs = 0.f;
#pragma unroll
  for (int i = 0; i < 24; ++i) { float d = v[i] - mean; qs += d * d; }
  qs = gred16(qs);
  float rs = rsqrtf(qs * (1.f / 384.f) + 1e-3f);
#pragma unroll
  for (int i = 0; i < 3; ++i) {
    int col = (s + 16 * i) * 8;
    f4 g0 = ld4(g + col), g1 = ld4(g + col + 4);
    f4 b0 = ld4(b + col), b1 = ld4(b + col + 4);
    bf16x8 o;
#pragma unroll
    for (int e = 0; e < 4; ++e) {
      o[e] = (__bf16)((v[i * 8 + e] - mean) * rs * g0[e] + b0[e]);
      o[4 + e] = (__bf16)((v[i * 8 + 4 + e] - mean) * rs * g1[e] + b1[e]);
    }
    st8h(out + base + col, o);
  }
}

// ---------------- segment rowlist build ----------------
__global__ __launch_bounds__(256) void hist2_k(const int* __restrict__ ukk,
                                               const int* __restrict__ ujk,
                                               int* __restrict__ ckk,
                                               int* __restrict__ cij) {
  int i = blockIdx.x * 256 + threadIdx.x;
  atomicAdd(&ckk[ukk[i]], 1);
  atomicAdd(&cij[ujk[i]], 1);
}

__device__ inline void scan_body(const int* cnt, int* off, int* curb, int G, int* ls) {
  int t = threadIdx.x;
  int per = G / 256;
  int base = t * per;
  int s = 0;
  for (int i = 0; i < per; ++i) s += cnt[base + i];
  ls[t] = s;
  __syncthreads();
  for (int o = 1; o < 256; o <<= 1) {
    int v = (t >= o) ? ls[t - o] : 0;
    __syncthreads();
    ls[t] += v;
    __syncthreads();
  }
  int run = (t == 0) ? 0 : ls[t - 1];
  for (int i = 0; i < per; ++i) {
    off[base + i] = run;
    run += cnt[base + i];
    curb[base + i] = 0;
  }
  if (t == 255) off[G] = run;
}

__global__ __launch_bounds__(256) void scan2_k(const int* ckk, int* okk, int* qkk,
                                               const int* cij, int* oij, int* qij) {
  __shared__ int ls[256];
  if (blockIdx.x == 0) scan_body(ckk, okk, qkk, 4096, ls);
  else scan_body(cij, oij, qij, 512, ls);
}

__global__ __launch_bounds__(256) void scatter2_k(const int* __restrict__ ukk,
                                                  const int* __restrict__ ujk,
                                                  const int* __restrict__ okk,
                                                  int* __restrict__ qkk,
                                                  int* __restrict__ rkk,
                                                  const int* __restrict__ oij,
                                                  int* __restrict__ qij,
                                                  int* __restrict__ rij) {
  int i = blockIdx.x * 256 + threadIdx.x;
  int g1 = ukk[i];
  rkk[okk[g1] + atomicAdd(&qkk[g1], 1)] = i;
  int g2 = ujk[i];
  rij[oij[g2] + atomicAdd(&qij[g2], 1)] = i;
}

// one block per group, 384 threads = one per column
__global__ __launch_bounds__(384) void segagg_k(const __bf16* __restrict__ L,
                                                const __bf16* __restrict__ Ft,
                                                const int* __restrict__ rows,
                                                const int* __restrict__ off,
                                                float* __restrict__ yb) {
  int g = blockIdx.x;
  int c = threadIdx.x;
  int s = off[g], e = off[g + 1];
  float mx = -3.0e38f;
  for (int p = s; p < e; ++p) {
    int r = rows[p];
    mx = fmaxf(mx, (float)L[(size_t)r * DD + c]);
  }
  float num = 0.f, den = 0.f;
  for (int p = s; p < e; ++p) {
    int r = rows[p];
    float lv = (float)L[(size_t)r * DD + c];
    float fv = (float)Ft[(size_t)r * DD + c];
    float ev = expf(lv - mx);
    den += ev;
    num += fv * ev;
  }
  yb[(size_t)g * DD + c] = num / (den + 1e-12f);
}

__global__ __launch_bounds__(256) void addgather_k(__bf16* __restrict__ X,
                                                   const __bf16* __restrict__ z,
                                                   const int* __restrict__ gid) {
  int i = blockIdx.x * 256 + threadIdx.x;
  int row = i / 48, c = (i - row * 48) * 8;
  int g = gid[row];
  size_t lo = (size_t)row * DD + c;
  bf16x8 a = ld8h(X + lo);
  bf16x8 zz = ld8h(z + (size_t)g * DD + c);
  bf16x8 o;
#pragma unroll
  for (int e = 0; e < 8; ++e) o[e] = (__bf16)((float)a[e] + (float)zz[e]);
  st8h(X + lo, o);
}

extern "C" void kernel_launch(void* const* d_in, const int* in_sizes, int n_in,
                              void* d_out, int out_size, void* d_ws, size_t ws_size,
                              hipStream_t stream) {
  const float* in_net = (const float*)d_in[0];
  const float* in_inp = (const float*)d_in[1];
  const float* in_corr = (const float*)d_in[2];
  const int* nix = (const int*)d_in[3];
  const int* njx = (const int*)d_in[4];
  const int* ukk = (const int*)d_in[5];
  const int* ujk = (const int*)d_in[6];
  auto F = [&](int i) { return (const float*)d_in[i]; };

  constexpr size_t MiB = 1024 * 1024;
  constexpr size_t SZ_ACT = (size_t)NR * DD * 2;
  char* ws = (char*)d_ws;
  __bf16* T2b = (__bf16*)(ws);
  __bf16* Fb = (__bf16*)(ws + SZ_ACT);
  __bf16* zb = (__bf16*)(ws + 2 * SZ_ACT);         // 3 MiB
  float* yb = (float*)(ws + 2 * SZ_ACT + 3 * MiB); // 6 MiB
  __bf16* T1b = (__bf16*)(ws + 60 * MiB);          // 24 MiB
  char* p = ws + 84 * MiB;
  int* rows_kk = (int*)p; p += (size_t)NR * 4;
  int* rows_ij = (int*)p; p += (size_t)NR * 4;
  int* off_kk = (int*)p; p += 8192 * 4;
  int* off_ij = (int*)p; p += 1024 * 4;
  int* cnt_kk = (int*)p; p += 4096 * 4;
  int* cnt_ij = (int*)p; p += 512 * 4;
  int* curb_kk = (int*)p; p += 4096 * 4;
  int* curb_ij = (int*)p; p += 512 * 4;
  __bf16* wt_all = (__bf16*)p; p += (size_t)18 * DD * DD * 2;
  __bf16* wt_corr1 = (__bf16*)p; p += (size_t)DD * CDMP * 2;
  __bf16* zpage = (__bf16*)p;

  const int widx[18] = {17, 19, 21, 23, 25, 27, 29, 31, 33, 35, 39, 41, 43, 47, 49, 51, 9, 13};
  WPtrs P;
  for (int i = 0; i < 18; ++i) P.w[i] = F(widx[i]);
  P.w[18] = F(7);
  auto WTp = [&](int i) { return wt_all + (size_t)i * DD * DD; };

  hipMemsetAsync(zpage, 0, 256, stream);
  hipMemsetAsync(cnt_kk, 0, 4096 * 4, stream);
  hipMemsetAsync(cnt_ij, 0, 512 * 4, stream);
  trans_all_k<<<dim3(1344, 19), 256, 0, stream>>>(P, wt_all);
  hist2_k<<<NR / 256, 256, 0, stream>>>(ukk, ujk, cnt_kk, cnt_ij);
  scan2_k<<<2, 256, 0, stream>>>(cnt_kk, off_kk, curb_kk, cnt_ij, off_ij, curb_ij);
  scatter2_k<<<NR / 256, 256, 0, stream>>>(ukk, ujk, off_kk, curb_kk, rows_kk,
                                           off_ij, curb_ij, rows_ij);

  auto G = [&](int epi, const void* A, const __bf16* WT, const float* bias,
               __bf16* OUT, const __bf16* XRES, const __bf16* GIN,
               const float* p0, const float* p1, const float* p2, const float* p3,
               float* fout, const float* n32, const float* i32,
               const int* idx, int M, int K, int Kr) {
    GP gp{A, WT, bias, OUT, XRES, GIN, p0, p1, p2, p3, fout, n32, i32, idx, zpage, M, K, Kr};
    dim3 g(M / 128), b(512);
    switch (epi) {
      case 0: gemm_k<0, 0><<<g, b, 0, stream>>>(gp); break;
      case 1: gemm_k<1, 0><<<g, b, 0, stream>>>(gp); break;
      case 2: gemm_k<2, 0><<<g, b, 0, stream>>>(gp); break;
      case 4: gemm_k<4, 0><<<g, b, 0, stream>>>(gp); break;
      case 5: gemm_k<5, 0><<<g, b, 0, stream>>>(gp); break;
      case 6: gemm_k<6, 0><<<g, b, 0, stream>>>(gp); break;
      case 7: gemm_k<7, 0><<<g, b, 0, stream>>>(gp); break;
      case 8: gemm_k<0, 1><<<g, b, 0, stream>>>(gp); break;  // AFP32 store
      case 9: gemm_k<1, 1><<<g, b, 0, stream>>>(gp); break;  // AFP32 relu
    }
  };
  auto GS = [&](int epi, const void* A, const __bf16* WT, const float* bias,
                __bf16* OUT, const int* idx, int M, int K) {
    G(epi, A, WT, bias, OUT, nullptr, nullptr, nullptr, nullptr, nullptr, nullptr,
      nullptr, nullptr, nullptr, idx, M, K, K);
  };
  // dual-B: same A, EPIA applied to (WTa->Oa), EPIB to (WTb->Ob); EPIB in {0,1}
  auto GD = [&](const void* A, const __bf16* WTa, const float* ba, __bf16* Oa,
                const __bf16* WTb, const float* bb, __bf16* Ob, int epib) {
    GP ga{A, WTa, ba, Oa, nullptr, nullptr, nullptr, nullptr, nullptr, nullptr,
          nullptr, nullptr, nullptr, nullptr, zpage, NR, DD, DD};
    GP gb{A, WTb, bb, Ob, nullptr, nullptr, nullptr, nullptr, nullptr, nullptr,
          nullptr, nullptr, nullptr, nullptr, zpage, NR, DD, DD};
    dim3 g(NR / 128), b(512);
    if (epib == 0) gemm_dual_k<0, 0><<<g, b, 0, stream>>>(ga, gb);
    else gemm_dual_k<0, 1><<<g, b, 0, stream>>>(ga, gb);
  };

  const int SEGB = NR * 48 / 256;

  // corr encoder (fp32 A read in-GEMM; Kr = 882 real row stride)
  G(9, in_corr, wt_corr1, F(8), T1b, nullptr, nullptr, nullptr, nullptr, nullptr,
    nullptr, nullptr, nullptr, nullptr, nullptr, NR, CDMP, CDM);       // relu(h1)
  G(4, T1b, WTp(16), F(10), T2b, nullptr, nullptr, F(11), F(12), nullptr, nullptr,
    nullptr, nullptr, nullptr, nullptr, NR, DD, DD);                   // relu(LN(h2))
  G(5, T2b, WTp(17), F(14), T1b, nullptr, nullptr, F(15), F(16), nullptr, nullptr,
    nullptr, in_net, in_inp, nullptr, NR, DD, DD);                     // T1b = net2
  // c1
  GS(1, T1b, WTp(0), F(18), T2b, nix, NR, DD);
  GS(2, T2b, WTp(1), F(20), T1b, nullptr, NR, DD);                     // net3
  // c2
  GS(1, T1b, WTp(2), F(22), T2b, njx, NR, DD);
  GS(2, T2b, WTp(3), F(24), T1b, nullptr, NR, DD);                     // net4
  // kk soft-agg: logits+feats in one dual launch
  GD(T1b, WTp(5), F(28), T2b, WTp(4), F(26), Fb, 0);
  segagg_k<<<4096, 384, 0, stream>>>(T2b, Fb, rows_kk, off_kk, yb);
  GS(8, yb, WTp(6), F(30), zb, nullptr, 4096, DD);
  addgather_k<<<SEGB, 256, 0, stream>>>(T1b, zb, ukk);                 // net5
  // ij soft-agg
  GD(T1b, WTp(8), F(34), T2b, WTp(7), F(32), Fb, 0);
  segagg_k<<<512, 384, 0, stream>>>(T2b, Fb, rows_ij, off_ij, yb);
  GS(8, yb, WTp(9), F(36), zb, nullptr, 512, DD);
  ln_ag_k<<<NR / 16, 256, 0, stream>>>(T1b, zb, ujk, F(37), F(38), T2b);  // x1
  // gated residual 1: gate + relu-hidden dual, then LN2-fused consumer
  GD(T2b, WTp(10), F(40), Fb, WTp(11), F(42), T1b, 1);
  G(6, T1b, WTp(12), F(44), T2b, T2b, Fb, F(45), F(46), nullptr, nullptr,
    nullptr, nullptr, nullptr, nullptr, NR, DD, DD);                   // x2 = LN2(net7)
  // gated residual 2 + final heads
  GD(T2b, WTp(13), F(48), Fb, WTp(14), F(50), T1b, 1);
  G(7, T1b, WTp(15), F(52), nullptr, T2b, Fb, F(53), F(54), F(55), F(56),
    (float*)d_out, nullptr, nullptr, nullptr, NR, DD, DD);             // out
}